// Round 1
// baseline (1962.859 us; speedup 1.0000x reference)
//
#include <hip/hip_runtime.h>

#define T_LEN 2048
#define E_DIM 1024
#define H_N 16
#define G_N 4
#define D_H 64
#define F_DIM 4096
#define V_SZ 32000
#define L_N 4

typedef __attribute__((ext_vector_type(8))) __bf16 bf16x8;
typedef __attribute__((ext_vector_type(4))) float f32x4;

__device__ __forceinline__ unsigned short f2bf(float f){
  unsigned int u = __float_as_uint(f);
  unsigned int r = (u + 0x7FFFu + ((u >> 16) & 1u)) >> 16;
  return (unsigned short)r;
}

__device__ __forceinline__ f32x4 mfma16(bf16x8 a, bf16x8 b, f32x4 c){
  return __builtin_amdgcn_mfma_f32_16x16x32_bf16(a, b, c, 0, 0, 0);
}

// ---------------- embed gather ----------------
__global__ __launch_bounds__(256) void embed_k(const float* __restrict__ emb,
                                               const int* __restrict__ tokens,
                                               float* __restrict__ x){
  int t = blockIdx.x;
  int tok = tokens[t];
  const float4* src = (const float4*)(emb + (size_t)tok * E_DIM);
  float4* dst = (float4*)(x + (size_t)t * E_DIM);
  dst[threadIdx.x] = src[threadIdx.x];
}

// ---------------- transpose + fp32->bf16 convert: dst[c][r] = src[r][c] ----------------
__global__ __launch_bounds__(256) void transpose_bf16(const float* __restrict__ src,
                                                      unsigned short* __restrict__ dst,
                                                      int R, int C){
  __shared__ float tile[32][33];
  int c0 = blockIdx.x * 32, r0 = blockIdx.y * 32;
  int tx = threadIdx.x & 31, ty = threadIdx.x >> 5;
  for (int i = 0; i < 4; i++){
    int r = ty + i * 8;
    tile[r][tx] = src[(size_t)(r0 + r) * C + c0 + tx];
  }
  __syncthreads();
  for (int i = 0; i < 4; i++){
    int r = ty + i * 8;
    dst[(size_t)(c0 + r) * R + r0 + tx] = f2bf(tile[tx][r]);
  }
}

// ---------------- rmsnorm (row of 1024) fp32 -> bf16, out = n*(1+w) ----------------
__global__ __launch_bounds__(256) void rmsnorm_k(const float* __restrict__ x,
                                                 const float* __restrict__ w,
                                                 unsigned short* __restrict__ out){
  const int t = blockIdx.x, tid = threadIdx.x;
  const float4 v = ((const float4*)(x + (size_t)t * E_DIM))[tid];
  float ss = v.x*v.x + v.y*v.y + v.z*v.z + v.w*v.w;
  for (int m = 1; m < 64; m <<= 1) ss += __shfl_xor(ss, m);
  __shared__ float red[4];
  if ((tid & 63) == 0) red[tid >> 6] = ss;
  __syncthreads();
  ss = red[0] + red[1] + red[2] + red[3];
  const float r = rsqrtf(ss * (1.0f / E_DIM) + 1e-6f);
  const float4 wv = ((const float4*)w)[tid];
  ushort4 o;
  o.x = f2bf(v.x * r * (1.0f + wv.x));
  o.y = f2bf(v.y * r * (1.0f + wv.y));
  o.z = f2bf(v.z * r * (1.0f + wv.z));
  o.w = f2bf(v.w * r * (1.0f + wv.w));
  ((ushort4*)(out + (size_t)t * E_DIM))[tid] = o;
}

// ---------------- GEMM: C[M][N] (+)= A[M][K](bf16) * Bt[N][K](bf16)^T ----------------
#define BM 128
#define BN 128
#define BK 32

template<bool ADD>
__global__ __launch_bounds__(256) void gemm_bt(const unsigned short* __restrict__ A,
                                               const unsigned short* __restrict__ Bt,
                                               float* __restrict__ C,
                                               int M, int N, int K){
  __shared__ unsigned short As[BM][BK + 8];
  __shared__ unsigned short Bs[BN][BK + 8];
  const int tid = threadIdx.x;
  const int lane = tid & 63, wid = tid >> 6;
  const int wm = wid >> 1, wn = wid & 1;
  const int m0 = blockIdx.y * BM, n0 = blockIdx.x * BN;
  const int l15 = lane & 15, l4 = lane >> 4;
  const int srow = tid >> 1;
  const int scol = (tid & 1) * 16;

  f32x4 acc[4][4] = {};

  for (int k0 = 0; k0 < K; k0 += BK){
    __syncthreads();
    const uint4* ga = (const uint4*)(A + (size_t)(m0 + srow) * K + k0 + scol);
    *(uint4*)&As[srow][scol]     = ga[0];
    *(uint4*)&As[srow][scol + 8] = ga[1];
    const uint4* gb = (const uint4*)(Bt + (size_t)(n0 + srow) * K + k0 + scol);
    *(uint4*)&Bs[srow][scol]     = gb[0];
    *(uint4*)&Bs[srow][scol + 8] = gb[1];
    __syncthreads();
    bf16x8 af[4], bfr[4];
    for (int i = 0; i < 4; i++){
      af[i]  = *(const bf16x8*)&As[wm * 64 + i * 16 + l15][l4 * 8];
      bfr[i] = *(const bf16x8*)&Bs[wn * 64 + i * 16 + l15][l4 * 8];
    }
    for (int i = 0; i < 4; i++)
      for (int j = 0; j < 4; j++)
        acc[i][j] = mfma16(af[i], bfr[j], acc[i][j]);
  }

  for (int i = 0; i < 4; i++)
    for (int j = 0; j < 4; j++){
      int col = n0 + wn * 64 + j * 16 + l15;
      for (int r = 0; r < 4; r++){
        int row = m0 + wm * 64 + i * 16 + l4 * 4 + r;
        size_t idx = (size_t)row * N + col;
        if (ADD) C[idx] += acc[i][j][r]; else C[idx] = acc[i][j][r];
      }
    }
}

// ---------------- q/k norm + rope + v transpose ----------------
__global__ __launch_bounds__(256) void qkvpost_k(const float* __restrict__ qkv,
                                                 const float* __restrict__ qn,
                                                 const float* __restrict__ kn,
                                                 unsigned short* __restrict__ qb,
                                                 unsigned short* __restrict__ kb,
                                                 unsigned short* __restrict__ vt){
  const int t = blockIdx.x;
  const int lane = threadIdx.x & 63, w = threadIdx.x >> 6;
  const int d = lane;
  // rope factors (first 16 dims rotated; freq index = d&7)
  const int fi = d & 7;
  const float invf = powf(10000.0f, -(float)fi * 0.125f);
  const float ang = (float)t * invf;
  const float c = cosf(ang), s = sinf(ang);

  // Q heads: wave w handles heads w*4 .. w*4+3
  for (int i = 0; i < 4; i++){
    int h = w * 4 + i;
    float v = qkv[(size_t)t * 2560 + h * 128 + d];
    float ss = v * v;
    for (int m = 1; m < 64; m <<= 1) ss += __shfl_xor(ss, m);
    float r = rsqrtf(ss * (1.0f / D_H) + 1e-6f);
    float xn = v * r * (1.0f + qn[d]);
    float partner = __shfl_xor(xn, 8);
    float o;
    if (d < 8)       o = xn * c - partner * s;
    else if (d < 16) o = xn * c + partner * s;
    else             o = xn;
    qb[((size_t)h * T_LEN + t) * D_H + d] = f2bf(o);
  }
  // K group g = w
  {
    float v = qkv[(size_t)t * 2560 + 2048 + w * 64 + d];
    float ss = v * v;
    for (int m = 1; m < 64; m <<= 1) ss += __shfl_xor(ss, m);
    float r = rsqrtf(ss * (1.0f / D_H) + 1e-6f);
    float xn = v * r * (1.0f + kn[d]);
    float partner = __shfl_xor(xn, 8);
    float o;
    if (d < 8)       o = xn * c - partner * s;
    else if (d < 16) o = xn * c + partner * s;
    else             o = xn;
    kb[((size_t)w * T_LEN + t) * D_H + d] = f2bf(o);
  }
  // V transposed: vt[g][d][t]
  {
    float v = qkv[(size_t)t * 2560 + 2304 + w * 64 + d];
    vt[((size_t)(w * 64 + d)) * T_LEN + t] = f2bf(v);
  }
}

// ---------------- flash attention, 1 wave, 16 q-rows, KV tiles of 32 ----------------
__global__ __launch_bounds__(64) void attn_k(const unsigned short* __restrict__ qb,
                                             const unsigned short* __restrict__ kb,
                                             const unsigned short* __restrict__ vt,
                                             const float* __restrict__ qkv,
                                             unsigned short* __restrict__ ctxg){
  const int qt = blockIdx.x, h = blockIdx.y;
  const int g = h >> 2;
  const int lane = threadIdx.x;
  const int l15 = lane & 15, l4 = lane >> 4;
  const int q0 = qt * 16;
  __shared__ unsigned short Pl[16][40];

  const bf16x8 aq0 = *(const bf16x8*)(qb + ((size_t)h * T_LEN + q0 + l15) * D_H + l4 * 8);
  const bf16x8 aq1 = *(const bf16x8*)(qb + ((size_t)h * T_LEN + q0 + l15) * D_H + 32 + l4 * 8);

  f32x4 acc[4] = {};
  float mrun[4], lrun[4];
  for (int j = 0; j < 4; j++){ mrun[j] = -1e30f; lrun[j] = 0.0f; }

  for (int kv0 = 0; kv0 <= q0 + 15; kv0 += 32){
    f32x4 sc[2];
    for (int cp = 0; cp < 2; cp++){
      const unsigned short* kbase = kb + ((size_t)g * T_LEN + kv0 + cp * 16 + l15) * D_H + l4 * 8;
      bf16x8 bk0 = *(const bf16x8*)(kbase);
      bf16x8 bk1 = *(const bf16x8*)(kbase + 32);
      f32x4 z = {0.f, 0.f, 0.f, 0.f};
      z = mfma16(aq0, bk0, z);
      z = mfma16(aq1, bk1, z);
      sc[cp] = z;
    }
    float resc[4];
    for (int j = 0; j < 4; j++){
      int r = q0 + l4 * 4 + j;
      for (int cp = 0; cp < 2; cp++){
        int col = kv0 + cp * 16 + l15;
        float sv = sc[cp][j];
        sc[cp][j] = (col <= r) ? sv * 0.125f : -1e30f;
      }
      float mx = fmaxf(sc[0][j], sc[1][j]);
      for (int off = 1; off < 16; off <<= 1) mx = fmaxf(mx, __shfl_xor(mx, off));
      float mnew = fmaxf(mrun[j], mx);
      float p0 = __expf(sc[0][j] - mnew);
      float p1 = __expf(sc[1][j] - mnew);
      sc[0][j] = p0; sc[1][j] = p1;
      float sum = p0 + p1;
      for (int off = 1; off < 16; off <<= 1) sum += __shfl_xor(sum, off);
      resc[j] = __expf(mrun[j] - mnew);
      lrun[j] = lrun[j] * resc[j] + sum;
      mrun[j] = mnew;
    }
    __syncthreads();
    for (int j = 0; j < 4; j++){
      int r = l4 * 4 + j;
      Pl[r][l15]      = f2bf(sc[0][j]);
      Pl[r][16 + l15] = f2bf(sc[1][j]);
      for (int nt = 0; nt < 4; nt++) acc[nt][j] *= resc[j];
    }
    __syncthreads();
    bf16x8 pa = *(const bf16x8*)&Pl[l15][l4 * 8];
    for (int nt = 0; nt < 4; nt++){
      bf16x8 bv = *(const bf16x8*)(vt + ((size_t)g * 64 + nt * 16 + l15) * T_LEN + kv0 + l4 * 8);
      acc[nt] = mfma16(pa, bv, acc[nt]);
    }
  }

  for (int j = 0; j < 4; j++){
    int r = q0 + l4 * 4 + j;
    float inv = 1.0f / lrun[j];
    for (int nt = 0; nt < 4; nt++){
      int d = nt * 16 + l15;
      float gate = qkv[(size_t)r * 2560 + h * 128 + 64 + d];
      float val = acc[nt][j] * inv * (1.0f / (1.0f + __expf(-gate)));
      ctxg[(size_t)r * (H_N * D_H) + h * D_H + d] = f2bf(val);
    }
  }
}

// ---------------- silu(u) * g -> bf16 ----------------
__global__ __launch_bounds__(256) void silumul_k(const float* __restrict__ ff,
                                                 unsigned short* __restrict__ hg){
  size_t idx = ((size_t)blockIdx.x * 256 + threadIdx.x) * 4;
  size_t t = idx >> 12;
  size_t j = idx & 4095;
  const float4 u = *(const float4*)(ff + t * 8192 + j);
  const float4 gv = *(const float4*)(ff + t * 8192 + 4096 + j);
  ushort4 o;
  o.x = f2bf(u.x / (1.0f + __expf(-u.x)) * gv.x);
  o.y = f2bf(u.y / (1.0f + __expf(-u.y)) * gv.y);
  o.z = f2bf(u.z / (1.0f + __expf(-u.z)) * gv.z);
  o.w = f2bf(u.w / (1.0f + __expf(-u.w)) * gv.w);
  *(ushort4*)(hg + idx) = o;
}

extern "C" void kernel_launch(void* const* d_in, const int* in_sizes, int n_in,
                              void* d_out, int out_size, void* d_ws, size_t ws_size,
                              hipStream_t stream){
  (void)in_sizes; (void)n_in; (void)out_size; (void)ws_size;
  const int*   tokens = (const int*)d_in[0];
  const float* emb    = (const float*)d_in[1];
  const float* Wq     = (const float*)d_in[2];
  const float* Wk     = (const float*)d_in[3];
  const float* Wv     = (const float*)d_in[4];
  const float* Wo     = (const float*)d_in[5];
  const float* qn     = (const float*)d_in[6];
  const float* kn     = (const float*)d_in[7];
  const float* n1     = (const float*)d_in[8];
  const float* n2     = (const float*)d_in[9];
  const float* f1     = (const float*)d_in[10];
  const float* f2     = (const float*)d_in[11];
  const float* f3     = (const float*)d_in[12];
  const float* fn     = (const float*)d_in[13];
  const float* head   = (const float*)d_in[14];
  float* out = (float*)d_out;

  char* ws = (char*)d_ws;
  size_t off = 0;
  auto alloc = [&](size_t bytes)->char*{
    char* p = ws + off;
    off += (bytes + 255) & ~(size_t)255;
    return p;
  };
  float*          x       = (float*)alloc((size_t)T_LEN * E_DIM * 4);
  unsigned short* hbf     = (unsigned short*)alloc((size_t)T_LEN * E_DIM * 2);
  float*          qkvf    = (float*)alloc((size_t)T_LEN * 2560 * 4);
  unsigned short* qb      = (unsigned short*)alloc((size_t)H_N * T_LEN * D_H * 2);
  unsigned short* kb      = (unsigned short*)alloc((size_t)G_N * T_LEN * D_H * 2);
  unsigned short* vt      = (unsigned short*)alloc((size_t)G_N * D_H * T_LEN * 2);
  unsigned short* ctxg    = (unsigned short*)alloc((size_t)T_LEN * E_DIM * 2);
  float*          ff12    = (float*)alloc((size_t)T_LEN * 2 * F_DIM * 4);
  unsigned short* hg      = (unsigned short*)alloc((size_t)T_LEN * F_DIM * 2);
  unsigned short* wt_qkv  = (unsigned short*)alloc((size_t)2560 * E_DIM * 2);
  unsigned short* wt_o    = (unsigned short*)alloc((size_t)E_DIM * E_DIM * 2);
  unsigned short* wt_f12  = (unsigned short*)alloc((size_t)2 * F_DIM * E_DIM * 2);
  unsigned short* wt_f3   = (unsigned short*)alloc((size_t)E_DIM * F_DIM * 2);
  unsigned short* wt_head = (unsigned short*)alloc((size_t)V_SZ * E_DIM * 2);

  embed_k<<<T_LEN, 256, 0, stream>>>(emb, tokens, x);
  transpose_bf16<<<dim3(V_SZ / 32, E_DIM / 32), 256, 0, stream>>>(head, wt_head, E_DIM, V_SZ);

  for (int l = 0; l < L_N; l++){
    transpose_bf16<<<dim3(2048 / 32, 32), 256, 0, stream>>>(Wq + (size_t)l * E_DIM * 2048, wt_qkv, E_DIM, 2048);
    transpose_bf16<<<dim3(256 / 32, 32), 256, 0, stream>>>(Wk + (size_t)l * E_DIM * 256, wt_qkv + (size_t)2048 * E_DIM, E_DIM, 256);
    transpose_bf16<<<dim3(256 / 32, 32), 256, 0, stream>>>(Wv + (size_t)l * E_DIM * 256, wt_qkv + (size_t)2304 * E_DIM, E_DIM, 256);
    transpose_bf16<<<dim3(32, 32), 256, 0, stream>>>(Wo + (size_t)l * E_DIM * E_DIM, wt_o, E_DIM, E_DIM);
    transpose_bf16<<<dim3(F_DIM / 32, 32), 256, 0, stream>>>(f1 + (size_t)l * E_DIM * F_DIM, wt_f12, E_DIM, F_DIM);
    transpose_bf16<<<dim3(F_DIM / 32, 32), 256, 0, stream>>>(f2 + (size_t)l * E_DIM * F_DIM, wt_f12 + (size_t)F_DIM * E_DIM, E_DIM, F_DIM);
    transpose_bf16<<<dim3(E_DIM / 32, F_DIM / 32), 256, 0, stream>>>(f3 + (size_t)l * F_DIM * E_DIM, wt_f3, F_DIM, E_DIM);

    rmsnorm_k<<<T_LEN, 256, 0, stream>>>(x, n1 + l * E_DIM, hbf);
    gemm_bt<false><<<dim3(2560 / BN, T_LEN / BM), 256, 0, stream>>>(hbf, wt_qkv, qkvf, T_LEN, 2560, E_DIM);
    qkvpost_k<<<T_LEN, 256, 0, stream>>>(qkvf, qn + l * D_H, kn + l * D_H, qb, kb, vt);
    attn_k<<<dim3(T_LEN / 16, H_N), 64, 0, stream>>>(qb, kb, vt, qkvf, ctxg);
    gemm_bt<true><<<dim3(E_DIM / BN, T_LEN / BM), 256, 0, stream>>>(ctxg, wt_o, x, T_LEN, E_DIM, E_DIM);

    rmsnorm_k<<<T_LEN, 256, 0, stream>>>(x, n2 + l * E_DIM, hbf);
    gemm_bt<false><<<dim3(2 * F_DIM / BN, T_LEN / BM), 256, 0, stream>>>(hbf, wt_f12, ff12, T_LEN, 2 * F_DIM, E_DIM);
    silumul_k<<<(T_LEN * F_DIM) / (256 * 4), 256, 0, stream>>>(ff12, hg);
    gemm_bt<true><<<dim3(E_DIM / BN, T_LEN / BM), 256, 0, stream>>>(hg, wt_f3, x, T_LEN, E_DIM, F_DIM);
  }

  rmsnorm_k<<<T_LEN, 256, 0, stream>>>(x, fn, hbf);
  gemm_bt<false><<<dim3(V_SZ / BN, T_LEN / BM), 256, 0, stream>>>(hbf, wt_head, out, T_LEN, V_SZ, E_DIM);
}

// Round 2
// 1813.874 us; speedup vs baseline: 1.0821x; 1.0821x over previous
//
#include <hip/hip_runtime.h>

#define T_LEN 2048
#define E_DIM 1024
#define H_N 16
#define G_N 4
#define D_H 64
#define F_DIM 4096
#define V_SZ 32000
#define L_N 4

typedef __attribute__((ext_vector_type(8))) __bf16 bf16x8;
typedef __attribute__((ext_vector_type(4))) float f32x4;

__device__ __forceinline__ unsigned short f2bf(float f){
  unsigned int u = __float_as_uint(f);
  unsigned int r = (u + 0x7FFFu + ((u >> 16) & 1u)) >> 16;
  return (unsigned short)r;
}

__device__ __forceinline__ f32x4 mfma16(bf16x8 a, bf16x8 b, f32x4 c){
  return __builtin_amdgcn_mfma_f32_16x16x32_bf16(a, b, c, 0, 0, 0);
}

__device__ __forceinline__ void gl16(const void* g, void* l){
  __builtin_amdgcn_global_load_lds((const __attribute__((address_space(1))) void*)g,
                                   (__attribute__((address_space(3))) void*)l, 16, 0, 0);
}

// ---------------- embed gather ----------------
__global__ __launch_bounds__(256) void embed_k(const float* __restrict__ emb,
                                               const int* __restrict__ tokens,
                                               float* __restrict__ x){
  int t = blockIdx.x;
  int tok = tokens[t];
  const float4* src = (const float4*)(emb + (size_t)tok * E_DIM);
  float4* dst = (float4*)(x + (size_t)t * E_DIM);
  dst[threadIdx.x] = src[threadIdx.x];
}

// ---------------- transpose + fp32->bf16 convert: dst[c][r] = src[r][c] ----------------
__global__ __launch_bounds__(256) void transpose_bf16(const float* __restrict__ src,
                                                      unsigned short* __restrict__ dst,
                                                      int R, int C){
  __shared__ float tile[32][33];
  int c0 = blockIdx.x * 32, r0 = blockIdx.y * 32;
  int tx = threadIdx.x & 31, ty = threadIdx.x >> 5;
  for (int i = 0; i < 4; i++){
    int r = ty + i * 8;
    tile[r][tx] = src[(size_t)(r0 + r) * C + c0 + tx];
  }
  __syncthreads();
  for (int i = 0; i < 4; i++){
    int r = ty + i * 8;
    dst[(size_t)(c0 + r) * R + r0 + tx] = f2bf(tile[tx][r]);
  }
}

// ---------------- rmsnorm (row of 1024) fp32 -> bf16, out = n*(1+w) ----------------
__global__ __launch_bounds__(256) void rmsnorm_k(const float* __restrict__ x,
                                                 const float* __restrict__ w,
                                                 unsigned short* __restrict__ out){
  const int t = blockIdx.x, tid = threadIdx.x;
  const float4 v = ((const float4*)(x + (size_t)t * E_DIM))[tid];
  float ss = v.x*v.x + v.y*v.y + v.z*v.z + v.w*v.w;
  for (int m = 1; m < 64; m <<= 1) ss += __shfl_xor(ss, m);
  __shared__ float red[4];
  if ((tid & 63) == 0) red[tid >> 6] = ss;
  __syncthreads();
  ss = red[0] + red[1] + red[2] + red[3];
  const float r = rsqrtf(ss * (1.0f / E_DIM) + 1e-6f);
  const float4 wv = ((const float4*)w)[tid];
  ushort4 o;
  o.x = f2bf(v.x * r * (1.0f + wv.x));
  o.y = f2bf(v.y * r * (1.0f + wv.y));
  o.z = f2bf(v.z * r * (1.0f + wv.z));
  o.w = f2bf(v.w * r * (1.0f + wv.w));
  ((ushort4*)(out + (size_t)t * E_DIM))[tid] = o;
}

// ---------------- GEMM: C[M][N] (+)= A[M][K](bf16) * Bt[N][K](bf16)^T ----------------
// m97 structure: linear LDS [128][32], global_load_lds width=16, 2-barrier loop.
// 1D grid, bm-fast ordering + chunked XCD swizzle so the 16 M-blocks of one
// N-panel co-run on one XCD (B tile fetched ~once per panel).
#define BM 128
#define BN 128
#define BK 32

template<bool ADD>
__global__ __launch_bounds__(256) void gemm_bt(const unsigned short* __restrict__ A,
                                               const unsigned short* __restrict__ Bt,
                                               float* __restrict__ C,
                                               int M, int N, int K){
  __shared__ unsigned short As[BM * BK];
  __shared__ unsigned short Bs[BN * BK];
  const int tid = threadIdx.x;
  const int lane = tid & 63, w = tid >> 6;
  const int wm = w >> 1, wn = w & 1;
  const int l15 = lane & 15, l4 = lane >> 4;

  // chunked XCD swizzle (grid size always % 8 == 0 here)
  const int chunk = gridDim.x >> 3;
  const int wgid = (blockIdx.x & 7) * chunk + (blockIdx.x >> 3);
  const int nm = M >> 7;
  const int bm = wgid % nm, bn = wgid / nm;
  const int m0 = bm * BM, n0 = bn * BN;

  // staging map: thread tid stages 16B landing at LDS flat byte tid*16 (+4KB for j=1)
  const int r0 = tid >> 2;            // row 0..63
  const int c0 = (tid & 3) << 3;      // elem col 0/8/16/24

  const unsigned short* gA0 = A  + (size_t)(m0 + r0) * K + c0;
  const unsigned short* gA1 = A  + (size_t)(m0 + 64 + r0) * K + c0;
  const unsigned short* gB0 = Bt + (size_t)(n0 + r0) * K + c0;
  const unsigned short* gB1 = Bt + (size_t)(n0 + 64 + r0) * K + c0;
  unsigned short* lA0 = As + w * 512;
  unsigned short* lA1 = As + 2048 + w * 512;
  unsigned short* lB0 = Bs + w * 512;
  unsigned short* lB1 = Bs + 2048 + w * 512;

  f32x4 acc[4][4] = {};

  for (int k0 = 0; k0 < K; k0 += BK){
    __syncthreads();
    gl16(gA0 + k0, lA0);
    gl16(gA1 + k0, lA1);
    gl16(gB0 + k0, lB0);
    gl16(gB1 + k0, lB1);
    __syncthreads();   // compiler emits s_waitcnt vmcnt(0) before s_barrier
    bf16x8 af[4], bfr[4];
    for (int i = 0; i < 4; i++){
      af[i]  = *(const bf16x8*)&As[(wm * 64 + i * 16 + l15) * BK + l4 * 8];
      bfr[i] = *(const bf16x8*)&Bs[(wn * 64 + i * 16 + l15) * BK + l4 * 8];
    }
    for (int i = 0; i < 4; i++)
      for (int j = 0; j < 4; j++)
        acc[i][j] = mfma16(af[i], bfr[j], acc[i][j]);
  }

  for (int i = 0; i < 4; i++)
    for (int j = 0; j < 4; j++){
      int col = n0 + wn * 64 + j * 16 + l15;
      for (int r = 0; r < 4; r++){
        int row = m0 + wm * 64 + i * 16 + l4 * 4 + r;
        size_t idx = (size_t)row * N + col;
        if (ADD) C[idx] += acc[i][j][r]; else C[idx] = acc[i][j][r];
      }
    }
}

// ---------------- q/k norm + rope + v transpose ----------------
__global__ __launch_bounds__(256) void qkvpost_k(const float* __restrict__ qkv,
                                                 const float* __restrict__ qn,
                                                 const float* __restrict__ kn,
                                                 unsigned short* __restrict__ qb,
                                                 unsigned short* __restrict__ kb,
                                                 unsigned short* __restrict__ vt){
  const int t = blockIdx.x;
  const int lane = threadIdx.x & 63, w = threadIdx.x >> 6;
  const int d = lane;
  const int fi = d & 7;
  const float invf = powf(10000.0f, -(float)fi * 0.125f);
  const float ang = (float)t * invf;
  const float c = cosf(ang), s = sinf(ang);

  for (int i = 0; i < 4; i++){
    int h = w * 4 + i;
    float v = qkv[(size_t)t * 2560 + h * 128 + d];
    float ss = v * v;
    for (int m = 1; m < 64; m <<= 1) ss += __shfl_xor(ss, m);
    float r = rsqrtf(ss * (1.0f / D_H) + 1e-6f);
    float xn = v * r * (1.0f + qn[d]);
    float partner = __shfl_xor(xn, 8);
    float o;
    if (d < 8)       o = xn * c - partner * s;
    else if (d < 16) o = xn * c + partner * s;
    else             o = xn;
    qb[((size_t)h * T_LEN + t) * D_H + d] = f2bf(o);
  }
  {
    float v = qkv[(size_t)t * 2560 + 2048 + w * 64 + d];
    float ss = v * v;
    for (int m = 1; m < 64; m <<= 1) ss += __shfl_xor(ss, m);
    float r = rsqrtf(ss * (1.0f / D_H) + 1e-6f);
    float xn = v * r * (1.0f + kn[d]);
    float partner = __shfl_xor(xn, 8);
    float o;
    if (d < 8)       o = xn * c - partner * s;
    else if (d < 16) o = xn * c + partner * s;
    else             o = xn;
    kb[((size_t)w * T_LEN + t) * D_H + d] = f2bf(o);
  }
  {
    float v = qkv[(size_t)t * 2560 + 2304 + w * 64 + d];
    vt[((size_t)(w * 64 + d)) * T_LEN + t] = f2bf(v);
  }
}

// ---------------- flash attention, 1 wave, 16 q-rows, KV tiles of 32 ----------------
__global__ __launch_bounds__(64) void attn_k(const unsigned short* __restrict__ qb,
                                             const unsigned short* __restrict__ kb,
                                             const unsigned short* __restrict__ vt,
                                             const float* __restrict__ qkv,
                                             unsigned short* __restrict__ ctxg){
  const int qt = blockIdx.x, h = blockIdx.y;
  const int g = h >> 2;
  const int lane = threadIdx.x;
  const int l15 = lane & 15, l4 = lane >> 4;
  const int q0 = qt * 16;
  __shared__ unsigned short Pl[16][40];

  const bf16x8 aq0 = *(const bf16x8*)(qb + ((size_t)h * T_LEN + q0 + l15) * D_H + l4 * 8);
  const bf16x8 aq1 = *(const bf16x8*)(qb + ((size_t)h * T_LEN + q0 + l15) * D_H + 32 + l4 * 8);

  f32x4 acc[4] = {};
  float mrun[4], lrun[4];
  for (int j = 0; j < 4; j++){ mrun[j] = -1e30f; lrun[j] = 0.0f; }

  for (int kv0 = 0; kv0 <= q0 + 15; kv0 += 32){
    f32x4 sc[2];
    for (int cp = 0; cp < 2; cp++){
      const unsigned short* kbase = kb + ((size_t)g * T_LEN + kv0 + cp * 16 + l15) * D_H + l4 * 8;
      bf16x8 bk0 = *(const bf16x8*)(kbase);
      bf16x8 bk1 = *(const bf16x8*)(kbase + 32);
      f32x4 z = {0.f, 0.f, 0.f, 0.f};
      z = mfma16(aq0, bk0, z);
      z = mfma16(aq1, bk1, z);
      sc[cp] = z;
    }
    float resc[4];
    for (int j = 0; j < 4; j++){
      int r = q0 + l4 * 4 + j;
      for (int cp = 0; cp < 2; cp++){
        int col = kv0 + cp * 16 + l15;
        float sv = sc[cp][j];
        sc[cp][j] = (col <= r) ? sv * 0.125f : -1e30f;
      }
      float mx = fmaxf(sc[0][j], sc[1][j]);
      for (int off = 1; off < 16; off <<= 1) mx = fmaxf(mx, __shfl_xor(mx, off));
      float mnew = fmaxf(mrun[j], mx);
      float p0 = __expf(sc[0][j] - mnew);
      float p1 = __expf(sc[1][j] - mnew);
      sc[0][j] = p0; sc[1][j] = p1;
      float sum = p0 + p1;
      for (int off = 1; off < 16; off <<= 1) sum += __shfl_xor(sum, off);
      resc[j] = __expf(mrun[j] - mnew);
      lrun[j] = lrun[j] * resc[j] + sum;
      mrun[j] = mnew;
    }
    __syncthreads();
    for (int j = 0; j < 4; j++){
      int r = l4 * 4 + j;
      Pl[r][l15]      = f2bf(sc[0][j]);
      Pl[r][16 + l15] = f2bf(sc[1][j]);
      for (int nt = 0; nt < 4; nt++) acc[nt][j] *= resc[j];
    }
    __syncthreads();
    bf16x8 pa = *(const bf16x8*)&Pl[l15][l4 * 8];
    for (int nt = 0; nt < 4; nt++){
      bf16x8 bv = *(const bf16x8*)(vt + ((size_t)g * 64 + nt * 16 + l15) * T_LEN + kv0 + l4 * 8);
      acc[nt] = mfma16(pa, bv, acc[nt]);
    }
  }

  for (int j = 0; j < 4; j++){
    int r = q0 + l4 * 4 + j;
    float inv = 1.0f / lrun[j];
    for (int nt = 0; nt < 4; nt++){
      int d = nt * 16 + l15;
      float gate = qkv[(size_t)r * 2560 + h * 128 + 64 + d];
      float val = acc[nt][j] * inv * (1.0f / (1.0f + __expf(-gate)));
      ctxg[(size_t)r * (H_N * D_H) + h * D_H + d] = f2bf(val);
    }
  }
}

// ---------------- silu(u) * g -> bf16 ----------------
__global__ __launch_bounds__(256) void silumul_k(const float* __restrict__ ff,
                                                 unsigned short* __restrict__ hg){
  size_t idx = ((size_t)blockIdx.x * 256 + threadIdx.x) * 4;
  size_t t = idx >> 12;
  size_t j = idx & 4095;
  const float4 u = *(const float4*)(ff + t * 8192 + j);
  const float4 gv = *(const float4*)(ff + t * 8192 + 4096 + j);
  ushort4 o;
  o.x = f2bf(u.x / (1.0f + __expf(-u.x)) * gv.x);
  o.y = f2bf(u.y / (1.0f + __expf(-u.y)) * gv.y);
  o.z = f2bf(u.z / (1.0f + __expf(-u.z)) * gv.z);
  o.w = f2bf(u.w / (1.0f + __expf(-u.w)) * gv.w);
  *(ushort4*)(hg + idx) = o;
}

extern "C" void kernel_launch(void* const* d_in, const int* in_sizes, int n_in,
                              void* d_out, int out_size, void* d_ws, size_t ws_size,
                              hipStream_t stream){
  (void)in_sizes; (void)n_in; (void)out_size; (void)ws_size;
  const int*   tokens = (const int*)d_in[0];
  const float* emb    = (const float*)d_in[1];
  const float* Wq     = (const float*)d_in[2];
  const float* Wk     = (const float*)d_in[3];
  const float* Wv     = (const float*)d_in[4];
  const float* Wo     = (const float*)d_in[5];
  const float* qn     = (const float*)d_in[6];
  const float* kn     = (const float*)d_in[7];
  const float* n1     = (const float*)d_in[8];
  const float* n2     = (const float*)d_in[9];
  const float* f1     = (const float*)d_in[10];
  const float* f2     = (const float*)d_in[11];
  const float* f3     = (const float*)d_in[12];
  const float* fn     = (const float*)d_in[13];
  const float* head   = (const float*)d_in[14];
  float* out = (float*)d_out;

  char* ws = (char*)d_ws;
  size_t off = 0;
  auto alloc = [&](size_t bytes)->char*{
    char* p = ws + off;
    off += (bytes + 255) & ~(size_t)255;
    return p;
  };
  float*          x       = (float*)alloc((size_t)T_LEN * E_DIM * 4);
  unsigned short* hbf     = (unsigned short*)alloc((size_t)T_LEN * E_DIM * 2);
  float*          qkvf    = (float*)alloc((size_t)T_LEN * 2560 * 4);
  unsigned short* qb      = (unsigned short*)alloc((size_t)H_N * T_LEN * D_H * 2);
  unsigned short* kb      = (unsigned short*)alloc((size_t)G_N * T_LEN * D_H * 2);
  unsigned short* vt      = (unsigned short*)alloc((size_t)G_N * D_H * T_LEN * 2);
  unsigned short* ctxg    = (unsigned short*)alloc((size_t)T_LEN * E_DIM * 2);
  float*          ff12    = (float*)alloc((size_t)T_LEN * 2 * F_DIM * 4);
  unsigned short* hg      = (unsigned short*)alloc((size_t)T_LEN * F_DIM * 2);
  unsigned short* wt_qkv  = (unsigned short*)alloc((size_t)2560 * E_DIM * 2);
  unsigned short* wt_o    = (unsigned short*)alloc((size_t)E_DIM * E_DIM * 2);
  unsigned short* wt_f12  = (unsigned short*)alloc((size_t)2 * F_DIM * E_DIM * 2);
  unsigned short* wt_f3   = (unsigned short*)alloc((size_t)E_DIM * F_DIM * 2);
  unsigned short* wt_head = (unsigned short*)alloc((size_t)V_SZ * E_DIM * 2);

  embed_k<<<T_LEN, 256, 0, stream>>>(emb, tokens, x);
  transpose_bf16<<<dim3(V_SZ / 32, E_DIM / 32), 256, 0, stream>>>(head, wt_head, E_DIM, V_SZ);

  for (int l = 0; l < L_N; l++){
    transpose_bf16<<<dim3(2048 / 32, 32), 256, 0, stream>>>(Wq + (size_t)l * E_DIM * 2048, wt_qkv, E_DIM, 2048);
    transpose_bf16<<<dim3(256 / 32, 32), 256, 0, stream>>>(Wk + (size_t)l * E_DIM * 256, wt_qkv + (size_t)2048 * E_DIM, E_DIM, 256);
    transpose_bf16<<<dim3(256 / 32, 32), 256, 0, stream>>>(Wv + (size_t)l * E_DIM * 256, wt_qkv + (size_t)2304 * E_DIM, E_DIM, 256);
    transpose_bf16<<<dim3(32, 32), 256, 0, stream>>>(Wo + (size_t)l * E_DIM * E_DIM, wt_o, E_DIM, E_DIM);
    transpose_bf16<<<dim3(F_DIM / 32, 32), 256, 0, stream>>>(f1 + (size_t)l * E_DIM * F_DIM, wt_f12, E_DIM, F_DIM);
    transpose_bf16<<<dim3(F_DIM / 32, 32), 256, 0, stream>>>(f2 + (size_t)l * E_DIM * F_DIM, wt_f12 + (size_t)F_DIM * E_DIM, E_DIM, F_DIM);
    transpose_bf16<<<dim3(E_DIM / 32, F_DIM / 32), 256, 0, stream>>>(f3 + (size_t)l * F_DIM * E_DIM, wt_f3, F_DIM, E_DIM);

    rmsnorm_k<<<T_LEN, 256, 0, stream>>>(x, n1 + l * E_DIM, hbf);
    gemm_bt<false><<<(T_LEN / BM) * (2560 / BN), 256, 0, stream>>>(hbf, wt_qkv, qkvf, T_LEN, 2560, E_DIM);
    qkvpost_k<<<T_LEN, 256, 0, stream>>>(qkvf, qn + l * D_H, kn + l * D_H, qb, kb, vt);
    attn_k<<<dim3(T_LEN / 16, H_N), 64, 0, stream>>>(qb, kb, vt, qkvf, ctxg);
    gemm_bt<true><<<(T_LEN / BM) * (E_DIM / BN), 256, 0, stream>>>(ctxg, wt_o, x, T_LEN, E_DIM, E_DIM);

    rmsnorm_k<<<T_LEN, 256, 0, stream>>>(x, n2 + l * E_DIM, hbf);
    gemm_bt<false><<<(T_LEN / BM) * (2 * F_DIM / BN), 256, 0, stream>>>(hbf, wt_f12, ff12, T_LEN, 2 * F_DIM, E_DIM);
    silumul_k<<<(T_LEN * F_DIM) / (256 * 4), 256, 0, stream>>>(ff12, hg);
    gemm_bt<true><<<(T_LEN / BM) * (E_DIM / BN), 256, 0, stream>>>(hg, wt_f3, x, T_LEN, E_DIM, F_DIM);
  }

  rmsnorm_k<<<T_LEN, 256, 0, stream>>>(x, fn, hbf);
  gemm_bt<false><<<(T_LEN / BM) * (V_SZ / BN), 256, 0, stream>>>(hbf, wt_head, out, T_LEN, V_SZ, E_DIM);
}

// Round 4
// 1709.326 us; speedup vs baseline: 1.1483x; 1.0612x over previous
//
#include <hip/hip_runtime.h>

#define T_LEN 2048
#define E_DIM 1024
#define H_N 16
#define G_N 4
#define D_H 64
#define F_DIM 4096
#define V_SZ 32000
#define L_N 4

typedef __attribute__((ext_vector_type(8))) __bf16 bf16x8;
typedef __attribute__((ext_vector_type(4))) float f32x4;

__device__ __forceinline__ unsigned short f2bf(float f){
  unsigned int u = __float_as_uint(f);
  unsigned int r = (u + 0x7FFFu + ((u >> 16) & 1u)) >> 16;
  return (unsigned short)r;
}

__device__ __forceinline__ f32x4 mfma16(bf16x8 a, bf16x8 b, f32x4 c){
  return __builtin_amdgcn_mfma_f32_16x16x32_bf16(a, b, c, 0, 0, 0);
}

__device__ __forceinline__ void gl16(const void* g, void* l){
  __builtin_amdgcn_global_load_lds((const __attribute__((address_space(1))) void*)g,
                                   (__attribute__((address_space(3))) void*)l, 16, 0, 0);
}

#define SBAR() __builtin_amdgcn_s_barrier()
#define LGK0() do{ asm volatile("s_waitcnt lgkmcnt(0)" ::: "memory"); __builtin_amdgcn_sched_barrier(0); }while(0)
#define VMC4() do{ asm volatile("s_waitcnt vmcnt(4)" ::: "memory"); __builtin_amdgcn_sched_barrier(0); }while(0)
#define VMC0() do{ asm volatile("s_waitcnt vmcnt(0)" ::: "memory"); __builtin_amdgcn_sched_barrier(0); }while(0)

// ---------------- embed gather ----------------
__global__ __launch_bounds__(256) void embed_k(const float* __restrict__ emb,
                                               const int* __restrict__ tokens,
                                               float* __restrict__ x){
  int t = blockIdx.x;
  int tok = tokens[t];
  const float4* src = (const float4*)(emb + (size_t)tok * E_DIM);
  float4* dst = (float4*)(x + (size_t)t * E_DIM);
  dst[threadIdx.x] = src[threadIdx.x];
}

// ---------------- transpose + fp32->bf16 convert: dst[c][r] = src[r][c] ----------------
__global__ __launch_bounds__(256) void transpose_bf16(const float* __restrict__ src,
                                                      unsigned short* __restrict__ dst,
                                                      int R, int C){
  __shared__ float tile[32][33];
  int c0 = blockIdx.x * 32, r0 = blockIdx.y * 32;
  int tx = threadIdx.x & 31, ty = threadIdx.x >> 5;
  for (int i = 0; i < 4; i++){
    int r = ty + i * 8;
    tile[r][tx] = src[(size_t)(r0 + r) * C + c0 + tx];
  }
  __syncthreads();
  for (int i = 0; i < 4; i++){
    int r = ty + i * 8;
    dst[(size_t)(c0 + r) * R + r0 + tx] = f2bf(tile[tx][r]);
  }
}

// ---------------- rmsnorm (row of 1024) fp32 -> bf16, out = n*(1+w) ----------------
__global__ __launch_bounds__(256) void rmsnorm_k(const float* __restrict__ x,
                                                 const float* __restrict__ w,
                                                 unsigned short* __restrict__ out){
  const int t = blockIdx.x, tid = threadIdx.x;
  const float4 v = ((const float4*)(x + (size_t)t * E_DIM))[tid];
  float ss = v.x*v.x + v.y*v.y + v.z*v.z + v.w*v.w;
  for (int m = 1; m < 64; m <<= 1) ss += __shfl_xor(ss, m);
  __shared__ float red[4];
  if ((tid & 63) == 0) red[tid >> 6] = ss;
  __syncthreads();
  ss = red[0] + red[1] + red[2] + red[3];
  const float r = rsqrtf(ss * (1.0f / E_DIM) + 1e-6f);
  const float4 wv = ((const float4*)w)[tid];
  ushort4 o;
  o.x = f2bf(v.x * r * (1.0f + wv.x));
  o.y = f2bf(v.y * r * (1.0f + wv.y));
  o.z = f2bf(v.z * r * (1.0f + wv.z));
  o.w = f2bf(v.w * r * (1.0f + wv.w));
  ((ushort4*)(out + (size_t)t * E_DIM))[tid] = o;
}

// ================= 128x128 GEMM (m97 structure) — for small-N matmuls =================
#define BM 128
#define BN 128
#define BK 32

template<bool ADD>
__global__ __launch_bounds__(256) void gemm_bt(const unsigned short* __restrict__ A,
                                               const unsigned short* __restrict__ Bt,
                                               float* __restrict__ C,
                                               int M, int N, int K){
  __shared__ unsigned short As[BM * BK];
  __shared__ unsigned short Bs[BN * BK];
  const int tid = threadIdx.x;
  const int lane = tid & 63, w = tid >> 6;
  const int wm = w >> 1, wn = w & 1;
  const int l15 = lane & 15, l4 = lane >> 4;

  const int chunk = gridDim.x >> 3;
  const int wgid = (blockIdx.x & 7) * chunk + (blockIdx.x >> 3);
  const int nm = M >> 7;
  const int bm = wgid % nm, bn = wgid / nm;
  const int m0 = bm * BM, n0 = bn * BN;

  const int r0 = tid >> 2;
  const int c0 = (tid & 3) << 3;

  const unsigned short* gA0 = A  + (size_t)(m0 + r0) * K + c0;
  const unsigned short* gA1 = A  + (size_t)(m0 + 64 + r0) * K + c0;
  const unsigned short* gB0 = Bt + (size_t)(n0 + r0) * K + c0;
  const unsigned short* gB1 = Bt + (size_t)(n0 + 64 + r0) * K + c0;
  unsigned short* lA0 = As + w * 512;
  unsigned short* lA1 = As + 2048 + w * 512;
  unsigned short* lB0 = Bs + w * 512;
  unsigned short* lB1 = Bs + 2048 + w * 512;

  f32x4 acc[4][4] = {};

  for (int k0 = 0; k0 < K; k0 += BK){
    __syncthreads();
    gl16(gA0 + k0, lA0);
    gl16(gA1 + k0, lA1);
    gl16(gB0 + k0, lB0);
    gl16(gB1 + k0, lB1);
    __syncthreads();
    bf16x8 af[4], bfr[4];
    for (int i = 0; i < 4; i++){
      af[i]  = *(const bf16x8*)&As[(wm * 64 + i * 16 + l15) * BK + l4 * 8];
      bfr[i] = *(const bf16x8*)&Bs[(wn * 64 + i * 16 + l15) * BK + l4 * 8];
    }
    for (int i = 0; i < 4; i++)
      for (int j = 0; j < 4; j++)
        acc[i][j] = mfma16(af[i], bfr[j], acc[i][j]);
  }

  for (int i = 0; i < 4; i++)
    for (int j = 0; j < 4; j++){
      int col = n0 + wn * 64 + j * 16 + l15;
      for (int r = 0; r < 4; r++){
        int row = m0 + wm * 64 + i * 16 + l4 * 4 + r;
        size_t idx = (size_t)row * N + col;
        if (ADD) C[idx] += acc[i][j][r]; else C[idx] = acc[i][j][r];
      }
    }
}

// ================= 256x256 8-phase GEMM (T2+T3+T4+T5) — for big-N matmuls =================
// BM=BN=256, BK=64, 8 waves (2m x 4n), per-wave 128x64 output, LDS 128 KiB.
// LDS: A slots [buf][half]: (buf*2+h)*16384 B; B slots at +65536 B. Half = [128][64] bf16.
// Swizzle: byte slot ^= (row&7)<<4 — applied inverse on global src (linear gl16 dest),
// and on ds_read addresses (rule #21: same involution both sides).
// Stage schedule (race-free from slot lifetimes; A slots dead after ph3, B after ph2):
//   ph1: kt+1.A0 (other buf)   ph2: kt+1.A1   ph3: kt+2.B0 (same buf)   ph4: kt+2.B1
// vmcnt(4) once per K-tile (tail: vmcnt(0)).
__global__ __launch_bounds__(512, 2) void gemm256(const unsigned short* __restrict__ A,
                                                  const unsigned short* __restrict__ Bt,
                                                  float* __restrict__ C,
                                                  int M, int N, int K){
  __shared__ unsigned short lds[65536];  // 128 KiB
  const int tid = threadIdx.x;
  const int lane = tid & 63, w = tid >> 6;
  const int wm = w >> 2, wn = w & 3;
  const int l15 = lane & 15, l4 = lane >> 4;

  const int chunk = gridDim.x >> 3;
  const int wgid = ((int)blockIdx.x & 7) * chunk + ((int)blockIdx.x >> 3);
  const int nm = M >> 8;
  const int bm = wgid % nm, bn = wgid / nm;
  const int m0 = bm * 256, n0 = bn * 256;
  const int NT = K >> 6;

  // staging lane geometry
  const int srow = (lane >> 3);          // 0..7 within 8-row strip
  const int scol = lane & 7;             // 16B slot 0..7

  auto stageA = [&](int b, int h, int kt){
    #pragma unroll
    for (int c = 0; c < 2; c++){
      int r = w * 16 + c * 8 + srow;
      const unsigned short* g = A + (size_t)(m0 + h * 128 + r) * K + kt * 64 + ((scol ^ (r & 7)) << 3);
      gl16(g, (char*)lds + (b * 2 + h) * 16384 + (w * 16 + c * 8) * 128);
    }
  };
  auto stageB = [&](int b, int h, int kt){
    #pragma unroll
    for (int c = 0; c < 2; c++){
      int r = w * 16 + c * 8 + srow;
      const unsigned short* g = Bt + (size_t)(n0 + h * 128 + r) * K + kt * 64 + ((scol ^ (r & 7)) << 3);
      gl16(g, (char*)lds + 65536 + (b * 2 + h) * 16384 + (w * 16 + c * 8) * 128);
    }
  };

  // frag-read slot bytes (row&7 == l15&7 for all frag rows)
  const int sl0 = ((l4)     ^ (l15 & 7)) << 4;   // ks=0
  const int sl1 = ((4 | l4) ^ (l15 & 7)) << 4;   // ks=1

  f32x4 acc[8][4] = {};
  bf16x8 aF[8], bF[8];

  // ---- prologue: kt0 {A0,A1,B0,B1} + kt1 {B0,B1}; kt1.A staged in kt0's ph1/ph2 ----
  stageA(0, 0, 0); stageA(0, 1, 0); stageB(0, 0, 0); stageB(0, 1, 0);
  if (NT > 1){ stageB(1, 0, 1); stageB(1, 1, 1); }
  VMC4();
  SBAR();

  for (int kt = 0; kt < NT; kt++){
    const int buf = kt & 1;
    const char* Ab = (const char*)lds + (buf * 2 + wm) * 16384;
    const char* Bb = (const char*)lds + 65536 + (buf * 2 + (wn >> 1)) * 16384;
    const int brbase = (wn & 1) * 64;

    // ---------------- PH1: LDA(mh=0) 8 + LDB(nh=0) 4 ; stage kt+1.A0 ----------------
    #pragma unroll
    for (int mf = 0; mf < 4; mf++){
      int r = mf * 16 + l15;
      aF[mf * 2 + 0] = *(const bf16x8*)(Ab + r * 128 + sl0);
      aF[mf * 2 + 1] = *(const bf16x8*)(Ab + r * 128 + sl1);
    }
    #pragma unroll
    for (int nf = 0; nf < 2; nf++){
      int r = brbase + nf * 16 + l15;
      bF[nf * 2 + 0] = *(const bf16x8*)(Bb + r * 128 + sl0);
      bF[nf * 2 + 1] = *(const bf16x8*)(Bb + r * 128 + sl1);
    }
    if (kt + 1 < NT) stageA(buf ^ 1, 0, kt + 1);
    SBAR(); LGK0();
    __builtin_amdgcn_s_setprio(1);
    #pragma unroll
    for (int mf = 0; mf < 4; mf++)
      #pragma unroll
      for (int nf = 0; nf < 2; nf++){
        acc[mf][nf] = mfma16(aF[mf * 2 + 0], bF[nf * 2 + 0], acc[mf][nf]);
        acc[mf][nf] = mfma16(aF[mf * 2 + 1], bF[nf * 2 + 1], acc[mf][nf]);
      }
    __builtin_amdgcn_s_setprio(0);
    SBAR();

    // ---------------- PH2: LDB(nh=1) 4 ; stage kt+1.A1 ----------------
    #pragma unroll
    for (int nf = 2; nf < 4; nf++){
      int r = brbase + nf * 16 + l15;
      bF[nf * 2 + 0] = *(const bf16x8*)(Bb + r * 128 + sl0);
      bF[nf * 2 + 1] = *(const bf16x8*)(Bb + r * 128 + sl1);
    }
    if (kt + 1 < NT) stageA(buf ^ 1, 1, kt + 1);
    SBAR(); LGK0();
    __builtin_amdgcn_s_setprio(1);
    #pragma unroll
    for (int mf = 0; mf < 4; mf++)
      #pragma unroll
      for (int nf = 2; nf < 4; nf++){
        acc[mf][nf] = mfma16(aF[mf * 2 + 0], bF[nf * 2 + 0], acc[mf][nf]);
        acc[mf][nf] = mfma16(aF[mf * 2 + 1], bF[nf * 2 + 1], acc[mf][nf]);
      }
    __builtin_amdgcn_s_setprio(0);
    SBAR();

    // ---------------- PH3: LDA(mh=1) 8 ; stage kt+2.B0 ----------------
    #pragma unroll
    for (int mf = 0; mf < 4; mf++){
      int r = 64 + mf * 16 + l15;
      aF[mf * 2 + 0] = *(const bf16x8*)(Ab + r * 128 + sl0);
      aF[mf * 2 + 1] = *(const bf16x8*)(Ab + r * 128 + sl1);
    }
    if (kt + 2 < NT) stageB(buf, 0, kt + 2);
    SBAR(); LGK0();
    __builtin_amdgcn_s_setprio(1);
    #pragma unroll
    for (int mf = 0; mf < 4; mf++)
      #pragma unroll
      for (int nf = 2; nf < 4; nf++){
        acc[4 + mf][nf] = mfma16(aF[mf * 2 + 0], bF[nf * 2 + 0], acc[4 + mf][nf]);
        acc[4 + mf][nf] = mfma16(aF[mf * 2 + 1], bF[nf * 2 + 1], acc[4 + mf][nf]);
      }
    __builtin_amdgcn_s_setprio(0);
    SBAR();

    // ---------------- PH4: stage kt+2.B1 ; MFMA (mh=1, nh=0) ----------------
    if (kt + 2 < NT) stageB(buf, 1, kt + 2);
    SBAR();
    __builtin_amdgcn_s_setprio(1);
    #pragma unroll
    for (int mf = 0; mf < 4; mf++)
      #pragma unroll
      for (int nf = 0; nf < 2; nf++){
        acc[4 + mf][nf] = mfma16(aF[mf * 2 + 0], bF[nf * 2 + 0], acc[4 + mf][nf]);
        acc[4 + mf][nf] = mfma16(aF[mf * 2 + 1], bF[nf * 2 + 1], acc[4 + mf][nf]);
      }
    __builtin_amdgcn_s_setprio(0);
    if (kt + 2 < NT) { VMC4(); } else { VMC0(); }
    SBAR();
  }

  // ---------------- epilogue: C write ----------------
  #pragma unroll
  for (int mfg = 0; mfg < 8; mfg++){
    #pragma unroll
    for (int nf = 0; nf < 4; nf++){
      int col = n0 + wn * 64 + nf * 16 + l15;
      int row0 = m0 + wm * 128 + mfg * 16 + l4 * 4;
      #pragma unroll
      for (int r = 0; r < 4; r++)
        C[(size_t)(row0 + r) * N + col] = acc[mfg][nf][r];
    }
  }
}

// ---------------- q/k norm + rope + v transpose ----------------
__global__ __launch_bounds__(256) void qkvpost_k(const float* __restrict__ qkv,
                                                 const float* __restrict__ qn,
                                                 const float* __restrict__ kn,
                                                 unsigned short* __restrict__ qb,
                                                 unsigned short* __restrict__ kb,
                                                 unsigned short* __restrict__ vt){
  const int t = blockIdx.x;
  const int lane = threadIdx.x & 63, w = threadIdx.x >> 6;
  const int d = lane;
  const int fi = d & 7;
  const float invf = powf(10000.0f, -(float)fi * 0.125f);
  const float ang = (float)t * invf;
  const float c = cosf(ang), s = sinf(ang);

  for (int i = 0; i < 4; i++){
    int h = w * 4 + i;
    float v = qkv[(size_t)t * 2560 + h * 128 + d];
    float ss = v * v;
    for (int m = 1; m < 64; m <<= 1) ss += __shfl_xor(ss, m);
    float r = rsqrtf(ss * (1.0f / D_H) + 1e-6f);
    float xn = v * r * (1.0f + qn[d]);
    float partner = __shfl_xor(xn, 8);
    float o;
    if (d < 8)       o = xn * c - partner * s;
    else if (d < 16) o = xn * c + partner * s;
    else             o = xn;
    qb[((size_t)h * T_LEN + t) * D_H + d] = f2bf(o);
  }
  {
    float v = qkv[(size_t)t * 2560 + 2048 + w * 64 + d];
    float ss = v * v;
    for (int m = 1; m < 64; m <<= 1) ss += __shfl_xor(ss, m);
    float r = rsqrtf(ss * (1.0f / D_H) + 1e-6f);
    float xn = v * r * (1.0f + kn[d]);
    float partner = __shfl_xor(xn, 8);
    float o;
    if (d < 8)       o = xn * c - partner * s;
    else if (d < 16) o = xn * c + partner * s;
    else             o = xn;
    kb[((size_t)w * T_LEN + t) * D_H + d] = f2bf(o);
  }
  {
    float v = qkv[(size_t)t * 2560 + 2304 + w * 64 + d];
    vt[((size_t)(w * 64 + d)) * T_LEN + t] = f2bf(v);
  }
}

// ---------------- flash attention, 1 wave, 16 q-rows, KV tiles of 32 ----------------
__global__ __launch_bounds__(64) void attn_k(const unsigned short* __restrict__ qb,
                                             const unsigned short* __restrict__ kb,
                                             const unsigned short* __restrict__ vt,
                                             const float* __restrict__ qkv,
                                             unsigned short* __restrict__ ctxg){
  const int qt = blockIdx.x, h = blockIdx.y;
  const int g = h >> 2;
  const int lane = threadIdx.x;
  const int l15 = lane & 15, l4 = lane >> 4;
  const int q0 = qt * 16;
  __shared__ unsigned short Pl[16][40];

  const bf16x8 aq0 = *(const bf16x8*)(qb + ((size_t)h * T_LEN + q0 + l15) * D_H + l4 * 8);
  const bf16x8 aq1 = *(const bf16x8*)(qb + ((size_t)h * T_LEN + q0 + l15) * D_H + 32 + l4 * 8);

  f32x4 acc[4] = {};
  float mrun[4], lrun[4];
  for (int j = 0; j < 4; j++){ mrun[j] = -1e30f; lrun[j] = 0.0f; }

  for (int kv0 = 0; kv0 <= q0 + 15; kv0 += 32){
    f32x4 sc[2];
    for (int cp = 0; cp < 2; cp++){
      const unsigned short* kbase = kb + ((size_t)g * T_LEN + kv0 + cp * 16 + l15) * D_H + l4 * 8;
      bf16x8 bk0 = *(const bf16x8*)(kbase);
      bf16x8 bk1 = *(const bf16x8*)(kbase + 32);
      f32x4 z = {0.f, 0.f, 0.f, 0.f};
      z = mfma16(aq0, bk0, z);
      z = mfma16(aq1, bk1, z);
      sc[cp] = z;
    }
    float resc[4];
    for (int j = 0; j < 4; j++){
      int r = q0 + l4 * 4 + j;
      for (int cp = 0; cp < 2; cp++){
        int col = kv0 + cp * 16 + l15;
        float sv = sc[cp][j];
        sc[cp][j] = (col <= r) ? sv * 0.125f : -1e30f;
      }
      float mx = fmaxf(sc[0][j], sc[1][j]);
      for (int off = 1; off < 16; off <<= 1) mx = fmaxf(mx, __shfl_xor(mx, off));
      float mnew = fmaxf(mrun[j], mx);
      float p0 = __expf(sc[0][j] - mnew);
      float p1 = __expf(sc[1][j] - mnew);
      sc[0][j] = p0; sc[1][j] = p1;
      float sum = p0 + p1;
      for (int off = 1; off < 16; off <<= 1) sum += __shfl_xor(sum, off);
      resc[j] = __expf(mrun[j] - mnew);
      lrun[j] = lrun[j] * resc[j] + sum;
      mrun[j] = mnew;
    }
    __syncthreads();
    for (int j = 0; j < 4; j++){
      int r = l4 * 4 + j;
      Pl[r][l15]      = f2bf(sc[0][j]);
      Pl[r][16 + l15] = f2bf(sc[1][j]);
      for (int nt = 0; nt < 4; nt++) acc[nt][j] *= resc[j];
    }
    __syncthreads();
    bf16x8 pa = *(const bf16x8*)&Pl[l15][l4 * 8];
    for (int nt = 0; nt < 4; nt++){
      bf16x8 bv = *(const bf16x8*)(vt + ((size_t)g * 64 + nt * 16 + l15) * T_LEN + kv0 + l4 * 8);
      acc[nt] = mfma16(pa, bv, acc[nt]);
    }
  }

  for (int j = 0; j < 4; j++){
    int r = q0 + l4 * 4 + j;
    float inv = 1.0f / lrun[j];
    for (int nt = 0; nt < 4; nt++){
      int d = nt * 16 + l15;
      float gate = qkv[(size_t)r * 2560 + h * 128 + 64 + d];
      float val = acc[nt][j] * inv * (1.0f / (1.0f + __expf(-gate)));
      ctxg[(size_t)r * (H_N * D_H) + h * D_H + d] = f2bf(val);
    }
  }
}

// ---------------- silu(u) * g -> bf16 ----------------
__global__ __launch_bounds__(256) void silumul_k(const float* __restrict__ ff,
                                                 unsigned short* __restrict__ hg){
  size_t idx = ((size_t)blockIdx.x * 256 + threadIdx.x) * 4;
  size_t t = idx >> 12;
  size_t j = idx & 4095;
  const float4 u = *(const float4*)(ff + t * 8192 + j);
  const float4 gv = *(const float4*)(ff + t * 8192 + 4096 + j);
  ushort4 o;
  o.x = f2bf(u.x / (1.0f + __expf(-u.x)) * gv.x);
  o.y = f2bf(u.y / (1.0f + __expf(-u.y)) * gv.y);
  o.z = f2bf(u.z / (1.0f + __expf(-u.z)) * gv.z);
  o.w = f2bf(u.w / (1.0f + __expf(-u.w)) * gv.w);
  *(ushort4*)(hg + idx) = o;
}

extern "C" void kernel_launch(void* const* d_in, const int* in_sizes, int n_in,
                              void* d_out, int out_size, void* d_ws, size_t ws_size,
                              hipStream_t stream){
  (void)in_sizes; (void)n_in; (void)out_size; (void)ws_size;
  const int*   tokens = (const int*)d_in[0];
  const float* emb    = (const float*)d_in[1];
  const float* Wq     = (const float*)d_in[2];
  const float* Wk     = (const float*)d_in[3];
  const float* Wv     = (const float*)d_in[4];
  const float* Wo     = (const float*)d_in[5];
  const float* qn     = (const float*)d_in[6];
  const float* kn     = (const float*)d_in[7];
  const float* n1     = (const float*)d_in[8];
  const float* n2     = (const float*)d_in[9];
  const float* f1     = (const float*)d_in[10];
  const float* f2     = (const float*)d_in[11];
  const float* f3     = (const float*)d_in[12];
  const float* fn     = (const float*)d_in[13];
  const float* head   = (const float*)d_in[14];
  float* out = (float*)d_out;

  char* ws = (char*)d_ws;
  size_t off = 0;
  auto alloc = [&](size_t bytes)->char*{
    char* p = ws + off;
    off += (bytes + 255) & ~(size_t)255;
    return p;
  };
  float*          x       = (float*)alloc((size_t)T_LEN * E_DIM * 4);
  unsigned short* hbf     = (unsigned short*)alloc((size_t)T_LEN * E_DIM * 2);
  float*          qkvf    = (float*)alloc((size_t)T_LEN * 2560 * 4);
  unsigned short* qb      = (unsigned short*)alloc((size_t)H_N * T_LEN * D_H * 2);
  unsigned short* kb      = (unsigned short*)alloc((size_t)G_N * T_LEN * D_H * 2);
  unsigned short* vt      = (unsigned short*)alloc((size_t)G_N * D_H * T_LEN * 2);
  unsigned short* ctxg    = (unsigned short*)alloc((size_t)T_LEN * E_DIM * 2);
  float*          ff12    = (float*)alloc((size_t)T_LEN * 2 * F_DIM * 4);
  unsigned short* hg      = (unsigned short*)alloc((size_t)T_LEN * F_DIM * 2);
  unsigned short* wt_qkv  = (unsigned short*)alloc((size_t)2560 * E_DIM * 2);
  unsigned short* wt_o    = (unsigned short*)alloc((size_t)E_DIM * E_DIM * 2);
  unsigned short* wt_f12  = (unsigned short*)alloc((size_t)2 * F_DIM * E_DIM * 2);
  unsigned short* wt_f3   = (unsigned short*)alloc((size_t)E_DIM * F_DIM * 2);
  unsigned short* wt_head = (unsigned short*)alloc((size_t)V_SZ * E_DIM * 2);

  embed_k<<<T_LEN, 256, 0, stream>>>(emb, tokens, x);
  transpose_bf16<<<dim3(V_SZ / 32, E_DIM / 32), 256, 0, stream>>>(head, wt_head, E_DIM, V_SZ);

  for (int l = 0; l < L_N; l++){
    transpose_bf16<<<dim3(2048 / 32, 32), 256, 0, stream>>>(Wq + (size_t)l * E_DIM * 2048, wt_qkv, E_DIM, 2048);
    transpose_bf16<<<dim3(256 / 32, 32), 256, 0, stream>>>(Wk + (size_t)l * E_DIM * 256, wt_qkv + (size_t)2048 * E_DIM, E_DIM, 256);
    transpose_bf16<<<dim3(256 / 32, 32), 256, 0, stream>>>(Wv + (size_t)l * E_DIM * 256, wt_qkv + (size_t)2304 * E_DIM, E_DIM, 256);
    transpose_bf16<<<dim3(32, 32), 256, 0, stream>>>(Wo + (size_t)l * E_DIM * E_DIM, wt_o, E_DIM, E_DIM);
    transpose_bf16<<<dim3(F_DIM / 32, 32), 256, 0, stream>>>(f1 + (size_t)l * E_DIM * F_DIM, wt_f12, E_DIM, F_DIM);
    transpose_bf16<<<dim3(F_DIM / 32, 32), 256, 0, stream>>>(f2 + (size_t)l * E_DIM * F_DIM, wt_f12 + (size_t)F_DIM * E_DIM, E_DIM, F_DIM);
    transpose_bf16<<<dim3(E_DIM / 32, F_DIM / 32), 256, 0, stream>>>(f3 + (size_t)l * F_DIM * E_DIM, wt_f3, F_DIM, E_DIM);

    rmsnorm_k<<<T_LEN, 256, 0, stream>>>(x, n1 + l * E_DIM, hbf);
    gemm_bt<false><<<(T_LEN / BM) * (2560 / BN), 256, 0, stream>>>(hbf, wt_qkv, qkvf, T_LEN, 2560, E_DIM);
    qkvpost_k<<<T_LEN, 256, 0, stream>>>(qkvf, qn + l * D_H, kn + l * D_H, qb, kb, vt);
    attn_k<<<dim3(T_LEN / 16, H_N), 64, 0, stream>>>(qb, kb, vt, qkvf, ctxg);
    gemm_bt<true><<<(T_LEN / BM) * (E_DIM / BN), 256, 0, stream>>>(ctxg, wt_o, x, T_LEN, E_DIM, E_DIM);

    rmsnorm_k<<<T_LEN, 256, 0, stream>>>(x, n2 + l * E_DIM, hbf);
    gemm256<<<(T_LEN / 256) * (2 * F_DIM / 256), 512, 0, stream>>>(hbf, wt_f12, ff12, T_LEN, 2 * F_DIM, E_DIM);
    silumul_k<<<(T_LEN * F_DIM) / (256 * 4), 256, 0, stream>>>(ff12, hg);
    gemm_bt<true><<<(T_LEN / BM) * (E_DIM / BN), 256, 0, stream>>>(hg, wt_f3, x, T_LEN, E_DIM, F_DIM);
  }

  rmsnorm_k<<<T_LEN, 256, 0, stream>>>(x, fn, hbf);
  gemm256<<<(T_LEN / 256) * (V_SZ / 256), 512, 0, stream>>>(hbf, wt_head, out, T_LEN, V_SZ, E_DIM);
}

// Round 5
// 1675.857 us; speedup vs baseline: 1.1713x; 1.0200x over previous
//
#include <hip/hip_runtime.h>

#define T_LEN 2048
#define E_DIM 1024
#define H_N 16
#define G_N 4
#define D_H 64
#define F_DIM 4096
#define V_SZ 32000
#define L_N 4

typedef __attribute__((ext_vector_type(8))) __bf16 bf16x8;
typedef __attribute__((ext_vector_type(4))) float f32x4;

__device__ __forceinline__ unsigned short f2bf(float f){
  unsigned int u = __float_as_uint(f);
  unsigned int r = (u + 0x7FFFu + ((u >> 16) & 1u)) >> 16;
  return (unsigned short)r;
}

__device__ __forceinline__ f32x4 mfma16(bf16x8 a, bf16x8 b, f32x4 c){
  return __builtin_amdgcn_mfma_f32_16x16x32_bf16(a, b, c, 0, 0, 0);
}

__device__ __forceinline__ void gl16(const void* g, void* l){
  __builtin_amdgcn_global_load_lds((const __attribute__((address_space(1))) void*)g,
                                   (__attribute__((address_space(3))) void*)l, 16, 0, 0);
}

#define SBAR() __builtin_amdgcn_s_barrier()
#define LGK0() do{ asm volatile("s_waitcnt lgkmcnt(0)" ::: "memory"); __builtin_amdgcn_sched_barrier(0); }while(0)
#define VMC4() do{ asm volatile("s_waitcnt vmcnt(4)" ::: "memory"); __builtin_amdgcn_sched_barrier(0); }while(0)
#define VMC0() do{ asm volatile("s_waitcnt vmcnt(0)" ::: "memory"); __builtin_amdgcn_sched_barrier(0); }while(0)

// 0.125 * log2(e): folded into Q so attention uses exp2 directly
#define QSCALE 0.1803368801111183f

// ---------------- embed gather ----------------
__global__ __launch_bounds__(256) void embed_k(const float* __restrict__ emb,
                                               const int* __restrict__ tokens,
                                               float* __restrict__ x){
  int t = blockIdx.x;
  int tok = tokens[t];
  const float4* src = (const float4*)(emb + (size_t)tok * E_DIM);
  float4* dst = (float4*)(x + (size_t)t * E_DIM);
  dst[threadIdx.x] = src[threadIdx.x];
}

// ---------------- transpose + fp32->bf16 convert: dst[c][r] = src[r][c] ----------------
__global__ __launch_bounds__(256) void transpose_bf16(const float* __restrict__ src,
                                                      unsigned short* __restrict__ dst,
                                                      int R, int C){
  __shared__ float tile[32][33];
  int c0 = blockIdx.x * 32, r0 = blockIdx.y * 32;
  int tx = threadIdx.x & 31, ty = threadIdx.x >> 5;
  for (int i = 0; i < 4; i++){
    int r = ty + i * 8;
    tile[r][tx] = src[(size_t)(r0 + r) * C + c0 + tx];
  }
  __syncthreads();
  for (int i = 0; i < 4; i++){
    int r = ty + i * 8;
    dst[(size_t)(c0 + r) * R + r0 + tx] = f2bf(tile[tx][r]);
  }
}

// ---------------- rmsnorm (row of 1024) fp32 -> bf16, out = n*(1+w) ----------------
__global__ __launch_bounds__(256) void rmsnorm_k(const float* __restrict__ x,
                                                 const float* __restrict__ w,
                                                 unsigned short* __restrict__ out){
  const int t = blockIdx.x, tid = threadIdx.x;
  const float4 v = ((const float4*)(x + (size_t)t * E_DIM))[tid];
  float ss = v.x*v.x + v.y*v.y + v.z*v.z + v.w*v.w;
  for (int m = 1; m < 64; m <<= 1) ss += __shfl_xor(ss, m);
  __shared__ float red[4];
  if ((tid & 63) == 0) red[tid >> 6] = ss;
  __syncthreads();
  ss = red[0] + red[1] + red[2] + red[3];
  const float r = rsqrtf(ss * (1.0f / E_DIM) + 1e-6f);
  const float4 wv = ((const float4*)w)[tid];
  ushort4 o;
  o.x = f2bf(v.x * r * (1.0f + wv.x));
  o.y = f2bf(v.y * r * (1.0f + wv.y));
  o.z = f2bf(v.z * r * (1.0f + wv.z));
  o.w = f2bf(v.w * r * (1.0f + wv.w));
  ((ushort4*)(out + (size_t)t * E_DIM))[tid] = o;
}

// ================= 64x128 GEMM (m97 structure, 256 thr) — small-N matmuls, full chip fill =================
// BM=64, BN=128, BK=32. 4 waves side by side in N (wave w -> cols w*32..w*32+31).
template<bool ADD>
__global__ __launch_bounds__(256) void gemm64_bt(const unsigned short* __restrict__ A,
                                                 const unsigned short* __restrict__ Bt,
                                                 float* __restrict__ C,
                                                 int M, int N, int K){
  __shared__ unsigned short As[64 * 32];
  __shared__ unsigned short Bs[128 * 32];
  const int tid = threadIdx.x;
  const int lane = tid & 63, w = tid >> 6;
  const int l15 = lane & 15, l4 = lane >> 4;

  const int chunk = gridDim.x >> 3;
  const int wgid = (blockIdx.x & 7) * chunk + (blockIdx.x >> 3);
  const int nm = M >> 6;
  const int bm = wgid % nm, bn = wgid / nm;
  const int m0 = bm * 64, n0 = bn * 128;

  const int r0 = tid >> 2;            // 0..63
  const int c0 = (tid & 3) << 3;      // 0/8/16/24

  const unsigned short* gA  = A  + (size_t)(m0 + r0) * K + c0;
  const unsigned short* gB0 = Bt + (size_t)(n0 + r0) * K + c0;
  const unsigned short* gB1 = Bt + (size_t)(n0 + 64 + r0) * K + c0;
  unsigned short* lA  = As + w * 512;
  unsigned short* lB0 = Bs + w * 512;
  unsigned short* lB1 = Bs + 2048 + w * 512;

  f32x4 acc[4][2] = {};

  for (int k0 = 0; k0 < K; k0 += 32){
    __syncthreads();
    gl16(gA  + k0, lA);
    gl16(gB0 + k0, lB0);
    gl16(gB1 + k0, lB1);
    __syncthreads();
    bf16x8 af[4], bfr[2];
    for (int i = 0; i < 4; i++)
      af[i] = *(const bf16x8*)&As[(i * 16 + l15) * 32 + l4 * 8];
    for (int j = 0; j < 2; j++)
      bfr[j] = *(const bf16x8*)&Bs[(w * 32 + j * 16 + l15) * 32 + l4 * 8];
    for (int i = 0; i < 4; i++)
      for (int j = 0; j < 2; j++)
        acc[i][j] = mfma16(af[i], bfr[j], acc[i][j]);
  }

  for (int i = 0; i < 4; i++)
    for (int j = 0; j < 2; j++){
      int col = n0 + w * 32 + j * 16 + l15;
      for (int r = 0; r < 4; r++){
        int row = m0 + i * 16 + l4 * 4 + r;
        size_t idx = (size_t)row * N + col;
        if (ADD) C[idx] += acc[i][j][r]; else C[idx] = acc[i][j][r];
      }
    }
}

// ================= 256x256 8-phase GEMM (T2+T3+T4+T5) — for big-N matmuls =================
__global__ __launch_bounds__(512, 2) void gemm256(const unsigned short* __restrict__ A,
                                                  const unsigned short* __restrict__ Bt,
                                                  float* __restrict__ C,
                                                  int M, int N, int K){
  __shared__ unsigned short lds[65536];  // 128 KiB
  const int tid = threadIdx.x;
  const int lane = tid & 63, w = tid >> 6;
  const int wm = w >> 2, wn = w & 3;
  const int l15 = lane & 15, l4 = lane >> 4;

  const int chunk = gridDim.x >> 3;
  const int wgid = ((int)blockIdx.x & 7) * chunk + ((int)blockIdx.x >> 3);
  const int nm = M >> 8;
  const int bm = wgid % nm, bn = wgid / nm;
  const int m0 = bm * 256, n0 = bn * 256;
  const int NT = K >> 6;

  const int srow = (lane >> 3);
  const int scol = lane & 7;

  auto stageA = [&](int b, int h, int kt){
    #pragma unroll
    for (int c = 0; c < 2; c++){
      int r = w * 16 + c * 8 + srow;
      const unsigned short* g = A + (size_t)(m0 + h * 128 + r) * K + kt * 64 + ((scol ^ (r & 7)) << 3);
      gl16(g, (char*)lds + (b * 2 + h) * 16384 + (w * 16 + c * 8) * 128);
    }
  };
  auto stageB = [&](int b, int h, int kt){
    #pragma unroll
    for (int c = 0; c < 2; c++){
      int r = w * 16 + c * 8 + srow;
      const unsigned short* g = Bt + (size_t)(n0 + h * 128 + r) * K + kt * 64 + ((scol ^ (r & 7)) << 3);
      gl16(g, (char*)lds + 65536 + (b * 2 + h) * 16384 + (w * 16 + c * 8) * 128);
    }
  };

  const int sl0 = ((l4)     ^ (l15 & 7)) << 4;
  const int sl1 = ((4 | l4) ^ (l15 & 7)) << 4;

  f32x4 acc[8][4] = {};
  bf16x8 aF[8], bF[8];

  stageA(0, 0, 0); stageA(0, 1, 0); stageB(0, 0, 0); stageB(0, 1, 0);
  if (NT > 1){ stageB(1, 0, 1); stageB(1, 1, 1); }
  VMC4();
  SBAR();

  for (int kt = 0; kt < NT; kt++){
    const int buf = kt & 1;
    const char* Ab = (const char*)lds + (buf * 2 + wm) * 16384;
    const char* Bb = (const char*)lds + 65536 + (buf * 2 + (wn >> 1)) * 16384;
    const int brbase = (wn & 1) * 64;

    // PH1
    #pragma unroll
    for (int mf = 0; mf < 4; mf++){
      int r = mf * 16 + l15;
      aF[mf * 2 + 0] = *(const bf16x8*)(Ab + r * 128 + sl0);
      aF[mf * 2 + 1] = *(const bf16x8*)(Ab + r * 128 + sl1);
    }
    #pragma unroll
    for (int nf = 0; nf < 2; nf++){
      int r = brbase + nf * 16 + l15;
      bF[nf * 2 + 0] = *(const bf16x8*)(Bb + r * 128 + sl0);
      bF[nf * 2 + 1] = *(const bf16x8*)(Bb + r * 128 + sl1);
    }
    if (kt + 1 < NT) stageA(buf ^ 1, 0, kt + 1);
    SBAR(); LGK0();
    __builtin_amdgcn_s_setprio(1);
    #pragma unroll
    for (int mf = 0; mf < 4; mf++)
      #pragma unroll
      for (int nf = 0; nf < 2; nf++){
        acc[mf][nf] = mfma16(aF[mf * 2 + 0], bF[nf * 2 + 0], acc[mf][nf]);
        acc[mf][nf] = mfma16(aF[mf * 2 + 1], bF[nf * 2 + 1], acc[mf][nf]);
      }
    __builtin_amdgcn_s_setprio(0);
    SBAR();

    // PH2
    #pragma unroll
    for (int nf = 2; nf < 4; nf++){
      int r = brbase + nf * 16 + l15;
      bF[nf * 2 + 0] = *(const bf16x8*)(Bb + r * 128 + sl0);
      bF[nf * 2 + 1] = *(const bf16x8*)(Bb + r * 128 + sl1);
    }
    if (kt + 1 < NT) stageA(buf ^ 1, 1, kt + 1);
    SBAR(); LGK0();
    __builtin_amdgcn_s_setprio(1);
    #pragma unroll
    for (int mf = 0; mf < 4; mf++)
      #pragma unroll
      for (int nf = 2; nf < 4; nf++){
        acc[mf][nf] = mfma16(aF[mf * 2 + 0], bF[nf * 2 + 0], acc[mf][nf]);
        acc[mf][nf] = mfma16(aF[mf * 2 + 1], bF[nf * 2 + 1], acc[mf][nf]);
      }
    __builtin_amdgcn_s_setprio(0);
    SBAR();

    // PH3
    #pragma unroll
    for (int mf = 0; mf < 4; mf++){
      int r = 64 + mf * 16 + l15;
      aF[mf * 2 + 0] = *(const bf16x8*)(Ab + r * 128 + sl0);
      aF[mf * 2 + 1] = *(const bf16x8*)(Ab + r * 128 + sl1);
    }
    if (kt + 2 < NT) stageB(buf, 0, kt + 2);
    SBAR(); LGK0();
    __builtin_amdgcn_s_setprio(1);
    #pragma unroll
    for (int mf = 0; mf < 4; mf++)
      #pragma unroll
      for (int nf = 2; nf < 4; nf++){
        acc[4 + mf][nf] = mfma16(aF[mf * 2 + 0], bF[nf * 2 + 0], acc[4 + mf][nf]);
        acc[4 + mf][nf] = mfma16(aF[mf * 2 + 1], bF[nf * 2 + 1], acc[4 + mf][nf]);
      }
    __builtin_amdgcn_s_setprio(0);
    SBAR();

    // PH4
    if (kt + 2 < NT) stageB(buf, 1, kt + 2);
    SBAR();
    __builtin_amdgcn_s_setprio(1);
    #pragma unroll
    for (int mf = 0; mf < 4; mf++)
      #pragma unroll
      for (int nf = 0; nf < 2; nf++){
        acc[4 + mf][nf] = mfma16(aF[mf * 2 + 0], bF[nf * 2 + 0], acc[4 + mf][nf]);
        acc[4 + mf][nf] = mfma16(aF[mf * 2 + 1], bF[nf * 2 + 1], acc[4 + mf][nf]);
      }
    __builtin_amdgcn_s_setprio(0);
    if (kt + 2 < NT) { VMC4(); } else { VMC0(); }
    SBAR();
  }

  #pragma unroll
  for (int mfg = 0; mfg < 8; mfg++){
    #pragma unroll
    for (int nf = 0; nf < 4; nf++){
      int col = n0 + wn * 64 + nf * 16 + l15;
      int row0 = m0 + wm * 128 + mfg * 16 + l4 * 4;
      #pragma unroll
      for (int r = 0; r < 4; r++)
        C[(size_t)(row0 + r) * N + col] = acc[mfg][nf][r];
    }
  }
}

// ---------------- q/k norm + rope + v transpose (Q pre-scaled by 0.125*log2e) ----------------
__global__ __launch_bounds__(256) void qkvpost_k(const float* __restrict__ qkv,
                                                 const float* __restrict__ qn,
                                                 const float* __restrict__ kn,
                                                 unsigned short* __restrict__ qb,
                                                 unsigned short* __restrict__ kb,
                                                 unsigned short* __restrict__ vt){
  const int t = blockIdx.x;
  const int lane = threadIdx.x & 63, w = threadIdx.x >> 6;
  const int d = lane;
  const int fi = d & 7;
  const float invf = powf(10000.0f, -(float)fi * 0.125f);
  const float ang = (float)t * invf;
  const float c = cosf(ang), s = sinf(ang);

  for (int i = 0; i < 4; i++){
    int h = w * 4 + i;
    float v = qkv[(size_t)t * 2560 + h * 128 + d];
    float ss = v * v;
    for (int m = 1; m < 64; m <<= 1) ss += __shfl_xor(ss, m);
    float r = rsqrtf(ss * (1.0f / D_H) + 1e-6f);
    float xn = v * r * (1.0f + qn[d]);
    float partner = __shfl_xor(xn, 8);
    float o;
    if (d < 8)       o = xn * c - partner * s;
    else if (d < 16) o = xn * c + partner * s;
    else             o = xn;
    qb[((size_t)h * T_LEN + t) * D_H + d] = f2bf(o * QSCALE);
  }
  {
    float v = qkv[(size_t)t * 2560 + 2048 + w * 64 + d];
    float ss = v * v;
    for (int m = 1; m < 64; m <<= 1) ss += __shfl_xor(ss, m);
    float r = rsqrtf(ss * (1.0f / D_H) + 1e-6f);
    float xn = v * r * (1.0f + kn[d]);
    float partner = __shfl_xor(xn, 8);
    float o;
    if (d < 8)       o = xn * c - partner * s;
    else if (d < 16) o = xn * c + partner * s;
    else             o = xn;
    kb[((size_t)w * T_LEN + t) * D_H + d] = f2bf(o);
  }
  {
    float v = qkv[(size_t)t * 2560 + 2304 + w * 64 + d];
    vt[((size_t)(w * 64 + d)) * T_LEN + t] = f2bf(v);
  }
}

// ---------------- flash attention, 1 wave, 16 q-rows, KV tiles of 64 ----------------
// scores pre-scaled (Q carries 0.125*log2e) -> exp2; denominator kept as per-lane
// partials (defer-sum), reduced once at the end.
__global__ __launch_bounds__(64) void attn_k(const unsigned short* __restrict__ qb,
                                             const unsigned short* __restrict__ kb,
                                             const unsigned short* __restrict__ vt,
                                             const float* __restrict__ qkv,
                                             unsigned short* __restrict__ ctxg){
  const int qt = blockIdx.x, h = blockIdx.y;
  const int g = h >> 2;
  const int lane = threadIdx.x;
  const int l15 = lane & 15, l4 = lane >> 4;
  const int q0 = qt * 16;
  __shared__ unsigned short Pl[16][72];

  const bf16x8 aq0 = *(const bf16x8*)(qb + ((size_t)h * T_LEN + q0 + l15) * D_H + l4 * 8);
  const bf16x8 aq1 = *(const bf16x8*)(qb + ((size_t)h * T_LEN + q0 + l15) * D_H + 32 + l4 * 8);

  f32x4 acc[4] = {};
  float mrun[4], lpart[4];
  for (int j = 0; j < 4; j++){ mrun[j] = -1e30f; lpart[j] = 0.0f; }

  for (int kv0 = 0; kv0 <= q0 + 15; kv0 += 64){
    f32x4 sc[4];
    #pragma unroll
    for (int cp = 0; cp < 4; cp++){
      const unsigned short* kbase = kb + ((size_t)g * T_LEN + kv0 + cp * 16 + l15) * D_H + l4 * 8;
      bf16x8 bk0 = *(const bf16x8*)(kbase);
      bf16x8 bk1 = *(const bf16x8*)(kbase + 32);
      f32x4 z = {0.f, 0.f, 0.f, 0.f};
      z = mfma16(aq0, bk0, z);
      z = mfma16(aq1, bk1, z);
      sc[cp] = z;
    }
    float resc[4];
    #pragma unroll
    for (int j = 0; j < 4; j++){
      int r = q0 + l4 * 4 + j;
      #pragma unroll
      for (int cp = 0; cp < 4; cp++){
        int col = kv0 + cp * 16 + l15;
        sc[cp][j] = (col <= r) ? sc[cp][j] : -1e30f;
      }
      float mx = fmaxf(fmaxf(sc[0][j], sc[1][j]), fmaxf(sc[2][j], sc[3][j]));
      for (int off = 1; off < 16; off <<= 1) mx = fmaxf(mx, __shfl_xor(mx, off));
      float mnew = fmaxf(mrun[j], mx);
      resc[j] = exp2f(mrun[j] - mnew);
      mrun[j] = mnew;
      float ssum = 0.0f;
      #pragma unroll
      for (int cp = 0; cp < 4; cp++){
        float pv = exp2f(sc[cp][j] - mnew);
        sc[cp][j] = pv;
        ssum += pv;
      }
      lpart[j] = lpart[j] * resc[j] + ssum;
      #pragma unroll
      for (int nt = 0; nt < 4; nt++) acc[nt][j] *= resc[j];
    }
    __syncthreads();
    #pragma unroll
    for (int j = 0; j < 4; j++)
      #pragma unroll
      for (int cp = 0; cp < 4; cp++)
        Pl[l4 * 4 + j][cp * 16 + l15] = f2bf(sc[cp][j]);
    __syncthreads();
    const bf16x8 pa0 = *(const bf16x8*)&Pl[l15][l4 * 8];
    const bf16x8 pa1 = *(const bf16x8*)&Pl[l15][32 + l4 * 8];
    #pragma unroll
    for (int nt = 0; nt < 4; nt++){
      const unsigned short* vbase = vt + ((size_t)g * 64 + nt * 16 + l15) * T_LEN + kv0;
      bf16x8 bv0 = *(const bf16x8*)(vbase + l4 * 8);
      bf16x8 bv1 = *(const bf16x8*)(vbase + 32 + l4 * 8);
      acc[nt] = mfma16(pa1, bv1, mfma16(pa0, bv0, acc[nt]));
    }
  }

  #pragma unroll
  for (int j = 0; j < 4; j++)
    for (int off = 1; off < 16; off <<= 1) lpart[j] += __shfl_xor(lpart[j], off);

  #pragma unroll
  for (int j = 0; j < 4; j++){
    int r = q0 + l4 * 4 + j;
    float inv = 1.0f / lpart[j];
    #pragma unroll
    for (int nt = 0; nt < 4; nt++){
      int d = nt * 16 + l15;
      float gate = qkv[(size_t)r * 2560 + h * 128 + 64 + d];
      float val = acc[nt][j] * inv * (1.0f / (1.0f + __expf(-gate)));
      ctxg[(size_t)r * (H_N * D_H) + h * D_H + d] = f2bf(val);
    }
  }
}

// ---------------- silu(u) * g -> bf16 ----------------
__global__ __launch_bounds__(256) void silumul_k(const float* __restrict__ ff,
                                                 unsigned short* __restrict__ hg){
  size_t idx = ((size_t)blockIdx.x * 256 + threadIdx.x) * 4;
  size_t t = idx >> 12;
  size_t j = idx & 4095;
  const float4 u = *(const float4*)(ff + t * 8192 + j);
  const float4 gv = *(const float4*)(ff + t * 8192 + 4096 + j);
  ushort4 o;
  o.x = f2bf(u.x / (1.0f + __expf(-u.x)) * gv.x);
  o.y = f2bf(u.y / (1.0f + __expf(-u.y)) * gv.y);
  o.z = f2bf(u.z / (1.0f + __expf(-u.z)) * gv.z);
  o.w = f2bf(u.w / (1.0f + __expf(-u.w)) * gv.w);
  *(ushort4*)(hg + idx) = o;
}

extern "C" void kernel_launch(void* const* d_in, const int* in_sizes, int n_in,
                              void* d_out, int out_size, void* d_ws, size_t ws_size,
                              hipStream_t stream){
  (void)in_sizes; (void)n_in; (void)out_size; (void)ws_size;
  const int*   tokens = (const int*)d_in[0];
  const float* emb    = (const float*)d_in[1];
  const float* Wq     = (const float*)d_in[2];
  const float* Wk     = (const float*)d_in[3];
  const float* Wv     = (const float*)d_in[4];
  const float* Wo     = (const float*)d_in[5];
  const float* qn     = (const float*)d_in[6];
  const float* kn     = (const float*)d_in[7];
  const float* n1     = (const float*)d_in[8];
  const float* n2     = (const float*)d_in[9];
  const float* f1     = (const float*)d_in[10];
  const float* f2     = (const float*)d_in[11];
  const float* f3     = (const float*)d_in[12];
  const float* fn     = (const float*)d_in[13];
  const float* head   = (const float*)d_in[14];
  float* out = (float*)d_out;

  char* ws = (char*)d_ws;
  size_t off = 0;
  auto alloc = [&](size_t bytes)->char*{
    char* p = ws + off;
    off += (bytes + 255) & ~(size_t)255;
    return p;
  };
  float*          x       = (float*)alloc((size_t)T_LEN * E_DIM * 4);
  unsigned short* hbf     = (unsigned short*)alloc((size_t)T_LEN * E_DIM * 2);
  float*          qkvf    = (float*)alloc((size_t)T_LEN * 2560 * 4);
  unsigned short* qb      = (unsigned short*)alloc((size_t)H_N * T_LEN * D_H * 2);
  unsigned short* kb      = (unsigned short*)alloc((size_t)G_N * T_LEN * D_H * 2);
  unsigned short* vt      = (unsigned short*)alloc((size_t)G_N * D_H * T_LEN * 2);
  unsigned short* ctxg    = (unsigned short*)alloc((size_t)T_LEN * E_DIM * 2);
  float*          ff12    = (float*)alloc((size_t)T_LEN * 2 * F_DIM * 4);
  unsigned short* hg      = (unsigned short*)alloc((size_t)T_LEN * F_DIM * 2);
  unsigned short* wt_qkv  = (unsigned short*)alloc((size_t)2560 * E_DIM * 2);
  unsigned short* wt_o    = (unsigned short*)alloc((size_t)E_DIM * E_DIM * 2);
  unsigned short* wt_f12  = (unsigned short*)alloc((size_t)2 * F_DIM * E_DIM * 2);
  unsigned short* wt_f3   = (unsigned short*)alloc((size_t)E_DIM * F_DIM * 2);
  unsigned short* wt_head = (unsigned short*)alloc((size_t)V_SZ * E_DIM * 2);

  embed_k<<<T_LEN, 256, 0, stream>>>(emb, tokens, x);
  transpose_bf16<<<dim3(V_SZ / 32, E_DIM / 32), 256, 0, stream>>>(head, wt_head, E_DIM, V_SZ);

  for (int l = 0; l < L_N; l++){
    transpose_bf16<<<dim3(2048 / 32, 32), 256, 0, stream>>>(Wq + (size_t)l * E_DIM * 2048, wt_qkv, E_DIM, 2048);
    transpose_bf16<<<dim3(256 / 32, 32), 256, 0, stream>>>(Wk + (size_t)l * E_DIM * 256, wt_qkv + (size_t)2048 * E_DIM, E_DIM, 256);
    transpose_bf16<<<dim3(256 / 32, 32), 256, 0, stream>>>(Wv + (size_t)l * E_DIM * 256, wt_qkv + (size_t)2304 * E_DIM, E_DIM, 256);
    transpose_bf16<<<dim3(32, 32), 256, 0, stream>>>(Wo + (size_t)l * E_DIM * E_DIM, wt_o, E_DIM, E_DIM);
    transpose_bf16<<<dim3(F_DIM / 32, 32), 256, 0, stream>>>(f1 + (size_t)l * E_DIM * F_DIM, wt_f12, E_DIM, F_DIM);
    transpose_bf16<<<dim3(F_DIM / 32, 32), 256, 0, stream>>>(f2 + (size_t)l * E_DIM * F_DIM, wt_f12 + (size_t)F_DIM * E_DIM, E_DIM, F_DIM);
    transpose_bf16<<<dim3(E_DIM / 32, F_DIM / 32), 256, 0, stream>>>(f3 + (size_t)l * F_DIM * E_DIM, wt_f3, F_DIM, E_DIM);

    rmsnorm_k<<<T_LEN, 256, 0, stream>>>(x, n1 + l * E_DIM, hbf);
    gemm64_bt<false><<<(T_LEN / 64) * (2560 / 128), 256, 0, stream>>>(hbf, wt_qkv, qkvf, T_LEN, 2560, E_DIM);
    qkvpost_k<<<T_LEN, 256, 0, stream>>>(qkvf, qn + l * D_H, kn + l * D_H, qb, kb, vt);
    attn_k<<<dim3(T_LEN / 16, H_N), 64, 0, stream>>>(qb, kb, vt, qkvf, ctxg);
    gemm64_bt<true><<<(T_LEN / 64) * (E_DIM / 128), 256, 0, stream>>>(ctxg, wt_o, x, T_LEN, E_DIM, E_DIM);

    rmsnorm_k<<<T_LEN, 256, 0, stream>>>(x, n2 + l * E_DIM, hbf);
    gemm256<<<(T_LEN / 256) * (2 * F_DIM / 256), 512, 0, stream>>>(hbf, wt_f12, ff12, T_LEN, 2 * F_DIM, E_DIM);
    silumul_k<<<(T_LEN * F_DIM) / (256 * 4), 256, 0, stream>>>(ff12, hg);
    gemm64_bt<true><<<(T_LEN / 64) * (E_DIM / 128), 256, 0, stream>>>(hg, wt_f3, x, T_LEN, E_DIM, F_DIM);
  }

  rmsnorm_k<<<T_LEN, 256, 0, stream>>>(x, fn, hbf);
  gemm256<<<(T_LEN / 256) * (V_SZ / 256), 512, 0, stream>>>(hbf, wt_head, out, T_LEN, V_SZ, E_DIM);
}

// Round 6
// 1568.899 us; speedup vs baseline: 1.2511x; 1.0682x over previous
//
#include <hip/hip_runtime.h>

#define T_LEN 2048
#define E_DIM 1024
#define H_N 16
#define G_N 4
#define D_H 64
#define F_DIM 4096
#define V_SZ 32000
#define L_N 4

typedef __attribute__((ext_vector_type(8))) __bf16 bf16x8;
typedef __attribute__((ext_vector_type(4))) float f32x4;

__device__ __forceinline__ unsigned short f2bf(float f){
  unsigned int u = __float_as_uint(f);
  unsigned int r = (u + 0x7FFFu + ((u >> 16) & 1u)) >> 16;
  return (unsigned short)r;
}

__device__ __forceinline__ f32x4 mfma16(bf16x8 a, bf16x8 b, f32x4 c){
  return __builtin_amdgcn_mfma_f32_16x16x32_bf16(a, b, c, 0, 0, 0);
}

__device__ __forceinline__ void gl16(const void* g, void* l){
  __builtin_amdgcn_global_load_lds((const __attribute__((address_space(1))) void*)g,
                                   (__attribute__((address_space(3))) void*)l, 16, 0, 0);
}

#define SBAR() __builtin_amdgcn_s_barrier()
#define LGK0() do{ asm volatile("s_waitcnt lgkmcnt(0)" ::: "memory"); __builtin_amdgcn_sched_barrier(0); }while(0)
#define VMC4() do{ asm volatile("s_waitcnt vmcnt(4)" ::: "memory"); __builtin_amdgcn_sched_barrier(0); }while(0)
#define VMC0() do{ asm volatile("s_waitcnt vmcnt(0)" ::: "memory"); __builtin_amdgcn_sched_barrier(0); }while(0)

// 0.125 * log2(e): folded into Q so attention uses exp2 directly
#define QSCALE 0.1803368801111183f

// ---------------- embed gather ----------------
__global__ __launch_bounds__(256) void embed_k(const float* __restrict__ emb,
                                               const int* __restrict__ tokens,
                                               float* __restrict__ x){
  int t = blockIdx.x;
  int tok = tokens[t];
  const float4* src = (const float4*)(emb + (size_t)tok * E_DIM);
  float4* dst = (float4*)(x + (size_t)t * E_DIM);
  dst[threadIdx.x] = src[threadIdx.x];
}

// ---------------- transpose + fp32->bf16: dst[c][r] = src[r][c] (head only) ----------------
__global__ __launch_bounds__(256) void transpose_bf16(const float* __restrict__ src,
                                                      unsigned short* __restrict__ dst,
                                                      int R, int C){
  __shared__ float tile[32][33];
  int c0 = blockIdx.x * 32, r0 = blockIdx.y * 32;
  int tx = threadIdx.x & 31, ty = threadIdx.x >> 5;
  for (int i = 0; i < 4; i++){
    int r = ty + i * 8;
    tile[r][tx] = src[(size_t)(r0 + r) * C + c0 + tx];
  }
  __syncthreads();
  for (int i = 0; i < 4; i++){
    int r = ty + i * 8;
    dst[(size_t)(c0 + r) * R + r0 + tx] = f2bf(tile[tx][r]);
  }
}

// ---------------- per-layer weight prep: all transposes in ONE launch ----------------
__device__ __forceinline__ void tr32(const float* __restrict__ src, unsigned short* __restrict__ dst,
                                     int R, int C, int bx, int by, float* tile /*32x33*/){
  int c0 = bx * 32, r0 = by * 32;
  int tx = threadIdx.x & 31, ty = threadIdx.x >> 5;
  for (int i = 0; i < 4; i++){
    int r = ty + i * 8;
    tile[r * 33 + tx] = src[(size_t)(r0 + r) * C + c0 + tx];
  }
  __syncthreads();
  for (int i = 0; i < 4; i++){
    int r = ty + i * 8;
    dst[(size_t)(c0 + r) * R + r0 + tx] = f2bf(tile[tx * 33 + r]);
  }
}

// wt_f12i layout: row n' (0..8191): q=n'/32, r=n'%32; r<16 -> f1 col q*16+r ; r>=16 -> f2 col q*16+(r-16)
__global__ __launch_bounds__(256) void prep_weights(const float* __restrict__ Wq, const float* __restrict__ Wk,
                                                    const float* __restrict__ Wv, const float* __restrict__ Wo,
                                                    const float* __restrict__ f1, const float* __restrict__ f2,
                                                    const float* __restrict__ f3,
                                                    unsigned short* __restrict__ wt_qkv,
                                                    unsigned short* __restrict__ wt_o,
                                                    unsigned short* __restrict__ wt_f12i,
                                                    unsigned short* __restrict__ wt_f3){
  __shared__ float sh[1100];
  int id = blockIdx.x;
  if (id < 2048){ tr32(Wq, wt_qkv, 1024, 2048, id & 63, id >> 6, sh); return; }
  id -= 2048;
  if (id < 256){ tr32(Wk, wt_qkv + 2048 * 1024, 1024, 256, id & 7, id >> 3, sh); return; }
  id -= 256;
  if (id < 256){ tr32(Wv, wt_qkv + 2304 * 1024, 1024, 256, id & 7, id >> 3, sh); return; }
  id -= 256;
  if (id < 1024){ tr32(Wo, wt_o, 1024, 1024, id & 31, id >> 5, sh); return; }
  id -= 1024;
  if (id < 4096){ tr32(f3, wt_f3, 4096, 1024, id & 31, id >> 5, sh); return; }
  id -= 4096;
  {
    int q = id & 255, kb = id >> 8;   // q: 16-col group of F; kb: 32-wide K block
    float* t1 = sh; float* t2 = sh + 32 * 17;
    int c = threadIdx.x & 15, kk0 = threadIdx.x >> 4;
    for (int p = 0; p < 2; p++){
      int kk = p * 16 + kk0;
      t1[kk * 17 + c] = f1[(size_t)(kb * 32 + kk) * F_DIM + q * 16 + c];
      t2[kk * 17 + c] = f2[(size_t)(kb * 32 + kk) * F_DIM + q * 16 + c];
    }
    __syncthreads();
    int kk = threadIdx.x & 31, rb = threadIdx.x >> 5;
    for (int i = 0; i < 4; i++){
      int r = i * 8 + rb;
      float v = (r < 16) ? t1[kk * 17 + r] : t2[kk * 17 + (r - 16)];
      wt_f12i[(size_t)(q * 32 + r) * 1024 + kb * 32 + kk] = f2bf(v);
    }
  }
}

// ---------------- rmsnorm (row of 1024) fp32 -> bf16, out = n*(1+w) ----------------
__global__ __launch_bounds__(256) void rmsnorm_k(const float* __restrict__ x,
                                                 const float* __restrict__ w,
                                                 unsigned short* __restrict__ out){
  const int t = blockIdx.x, tid = threadIdx.x;
  const float4 v = ((const float4*)(x + (size_t)t * E_DIM))[tid];
  float ss = v.x*v.x + v.y*v.y + v.z*v.z + v.w*v.w;
  for (int m = 1; m < 64; m <<= 1) ss += __shfl_xor(ss, m);
  __shared__ float red[4];
  if ((tid & 63) == 0) red[tid >> 6] = ss;
  __syncthreads();
  ss = red[0] + red[1] + red[2] + red[3];
  const float r = rsqrtf(ss * (1.0f / E_DIM) + 1e-6f);
  const float4 wv = ((const float4*)w)[tid];
  ushort4 o;
  o.x = f2bf(v.x * r * (1.0f + wv.x));
  o.y = f2bf(v.y * r * (1.0f + wv.y));
  o.z = f2bf(v.z * r * (1.0f + wv.z));
  o.w = f2bf(v.w * r * (1.0f + wv.w));
  ((ushort4*)(out + (size_t)t * E_DIM))[tid] = o;
}

// ================= 64x128 GEMM (m97 structure, 256 thr) — small-N matmuls =================
template<bool ADD>
__global__ __launch_bounds__(256) void gemm64_bt(const unsigned short* __restrict__ A,
                                                 const unsigned short* __restrict__ Bt,
                                                 float* __restrict__ C,
                                                 int M, int N, int K){
  __shared__ unsigned short As[64 * 32];
  __shared__ unsigned short Bs[128 * 32];
  const int tid = threadIdx.x;
  const int lane = tid & 63, w = tid >> 6;
  const int l15 = lane & 15, l4 = lane >> 4;

  const int chunk = gridDim.x >> 3;
  const int wgid = (blockIdx.x & 7) * chunk + (blockIdx.x >> 3);
  const int nm = M >> 6;
  const int bm = wgid % nm, bn = wgid / nm;
  const int m0 = bm * 64, n0 = bn * 128;

  const int r0 = tid >> 2;
  const int c0 = (tid & 3) << 3;

  const unsigned short* gA  = A  + (size_t)(m0 + r0) * K + c0;
  const unsigned short* gB0 = Bt + (size_t)(n0 + r0) * K + c0;
  const unsigned short* gB1 = Bt + (size_t)(n0 + 64 + r0) * K + c0;
  unsigned short* lA  = As + w * 512;
  unsigned short* lB0 = Bs + w * 512;
  unsigned short* lB1 = Bs + 2048 + w * 512;

  f32x4 acc[4][2] = {};

  for (int k0 = 0; k0 < K; k0 += 32){
    __syncthreads();
    gl16(gA  + k0, lA);
    gl16(gB0 + k0, lB0);
    gl16(gB1 + k0, lB1);
    __syncthreads();
    bf16x8 af[4], bfr[2];
    for (int i = 0; i < 4; i++)
      af[i] = *(const bf16x8*)&As[(i * 16 + l15) * 32 + l4 * 8];
    for (int j = 0; j < 2; j++)
      bfr[j] = *(const bf16x8*)&Bs[(w * 32 + j * 16 + l15) * 32 + l4 * 8];
    for (int i = 0; i < 4; i++)
      for (int j = 0; j < 2; j++)
        acc[i][j] = mfma16(af[i], bfr[j], acc[i][j]);
  }

  for (int i = 0; i < 4; i++)
    for (int j = 0; j < 2; j++){
      int col = n0 + w * 32 + j * 16 + l15;
      for (int r = 0; r < 4; r++){
        int row = m0 + i * 16 + l4 * 4 + r;
        size_t idx = (size_t)row * N + col;
        if (ADD) C[idx] += acc[i][j][r]; else C[idx] = acc[i][j][r];
      }
    }
}

// ================= 256x256 8-phase GEMM (T2+T3+T4+T5) =================
// EPI=0: plain fp32 store to outF[M][N]. EPI=1: f1/f2-interleaved silu-mul epilogue,
// bf16 store to outH[M][N/2] (weights must be wt_f12i layout).
template<int EPI>
__global__ __launch_bounds__(512, 2) void gemm256(const unsigned short* __restrict__ A,
                                                  const unsigned short* __restrict__ Bt,
                                                  float* __restrict__ outF,
                                                  unsigned short* __restrict__ outH,
                                                  int M, int N, int K){
  __shared__ unsigned short lds[65536];  // 128 KiB
  const int tid = threadIdx.x;
  const int lane = tid & 63, w = tid >> 6;
  const int wm = w >> 2, wn = w & 3;
  const int l15 = lane & 15, l4 = lane >> 4;

  const int chunk = gridDim.x >> 3;
  const int wgid = ((int)blockIdx.x & 7) * chunk + ((int)blockIdx.x >> 3);
  const int nm = M >> 8;
  const int bm = wgid % nm, bn = wgid / nm;
  const int m0 = bm * 256, n0 = bn * 256;
  const int NT = K >> 6;

  const int srow = (lane >> 3);
  const int scol = lane & 7;

  auto stageA = [&](int b, int h, int kt){
    #pragma unroll
    for (int c = 0; c < 2; c++){
      int r = w * 16 + c * 8 + srow;
      const unsigned short* g = A + (size_t)(m0 + h * 128 + r) * K + kt * 64 + ((scol ^ (r & 7)) << 3);
      gl16(g, (char*)lds + (b * 2 + h) * 16384 + (w * 16 + c * 8) * 128);
    }
  };
  auto stageB = [&](int b, int h, int kt){
    #pragma unroll
    for (int c = 0; c < 2; c++){
      int r = w * 16 + c * 8 + srow;
      const unsigned short* g = Bt + (size_t)(n0 + h * 128 + r) * K + kt * 64 + ((scol ^ (r & 7)) << 3);
      gl16(g, (char*)lds + 65536 + (b * 2 + h) * 16384 + (w * 16 + c * 8) * 128);
    }
  };

  const int sl0 = ((l4)     ^ (l15 & 7)) << 4;
  const int sl1 = ((4 | l4) ^ (l15 & 7)) << 4;

  f32x4 acc[8][4] = {};
  bf16x8 aF[8], bF[8];

  stageA(0, 0, 0); stageA(0, 1, 0); stageB(0, 0, 0); stageB(0, 1, 0);
  if (NT > 1){ stageB(1, 0, 1); stageB(1, 1, 1); }
  VMC4();
  SBAR();

  for (int kt = 0; kt < NT; kt++){
    const int buf = kt & 1;
    const char* Ab = (const char*)lds + (buf * 2 + wm) * 16384;
    const char* Bb = (const char*)lds + 65536 + (buf * 2 + (wn >> 1)) * 16384;
    const int brbase = (wn & 1) * 64;

    // PH1
    #pragma unroll
    for (int mf = 0; mf < 4; mf++){
      int r = mf * 16 + l15;
      aF[mf * 2 + 0] = *(const bf16x8*)(Ab + r * 128 + sl0);
      aF[mf * 2 + 1] = *(const bf16x8*)(Ab + r * 128 + sl1);
    }
    #pragma unroll
    for (int nf = 0; nf < 2; nf++){
      int r = brbase + nf * 16 + l15;
      bF[nf * 2 + 0] = *(const bf16x8*)(Bb + r * 128 + sl0);
      bF[nf * 2 + 1] = *(const bf16x8*)(Bb + r * 128 + sl1);
    }
    if (kt + 1 < NT) stageA(buf ^ 1, 0, kt + 1);
    SBAR(); LGK0();
    __builtin_amdgcn_s_setprio(1);
    #pragma unroll
    for (int mf = 0; mf < 4; mf++)
      #pragma unroll
      for (int nf = 0; nf < 2; nf++){
        acc[mf][nf] = mfma16(aF[mf * 2 + 0], bF[nf * 2 + 0], acc[mf][nf]);
        acc[mf][nf] = mfma16(aF[mf * 2 + 1], bF[nf * 2 + 1], acc[mf][nf]);
      }
    __builtin_amdgcn_s_setprio(0);
    SBAR();

    // PH2
    #pragma unroll
    for (int nf = 2; nf < 4; nf++){
      int r = brbase + nf * 16 + l15;
      bF[nf * 2 + 0] = *(const bf16x8*)(Bb + r * 128 + sl0);
      bF[nf * 2 + 1] = *(const bf16x8*)(Bb + r * 128 + sl1);
    }
    if (kt + 1 < NT) stageA(buf ^ 1, 1, kt + 1);
    SBAR(); LGK0();
    __builtin_amdgcn_s_setprio(1);
    #pragma unroll
    for (int mf = 0; mf < 4; mf++)
      #pragma unroll
      for (int nf = 2; nf < 4; nf++){
        acc[mf][nf] = mfma16(aF[mf * 2 + 0], bF[nf * 2 + 0], acc[mf][nf]);
        acc[mf][nf] = mfma16(aF[mf * 2 + 1], bF[nf * 2 + 1], acc[mf][nf]);
      }
    __builtin_amdgcn_s_setprio(0);
    SBAR();

    // PH3
    #pragma unroll
    for (int mf = 0; mf < 4; mf++){
      int r = 64 + mf * 16 + l15;
      aF[mf * 2 + 0] = *(const bf16x8*)(Ab + r * 128 + sl0);
      aF[mf * 2 + 1] = *(const bf16x8*)(Ab + r * 128 + sl1);
    }
    if (kt + 2 < NT) stageB(buf, 0, kt + 2);
    SBAR(); LGK0();
    __builtin_amdgcn_s_setprio(1);
    #pragma unroll
    for (int mf = 0; mf < 4; mf++)
      #pragma unroll
      for (int nf = 2; nf < 4; nf++){
        acc[4 + mf][nf] = mfma16(aF[mf * 2 + 0], bF[nf * 2 + 0], acc[4 + mf][nf]);
        acc[4 + mf][nf] = mfma16(aF[mf * 2 + 1], bF[nf * 2 + 1], acc[4 + mf][nf]);
      }
    __builtin_amdgcn_s_setprio(0);
    SBAR();

    // PH4
    if (kt + 2 < NT) stageB(buf, 1, kt + 2);
    SBAR();
    __builtin_amdgcn_s_setprio(1);
    #pragma unroll
    for (int mf = 0; mf < 4; mf++)
      #pragma unroll
      for (int nf = 0; nf < 2; nf++){
        acc[4 + mf][nf] = mfma16(aF[mf * 2 + 0], bF[nf * 2 + 0], acc[4 + mf][nf]);
        acc[4 + mf][nf] = mfma16(aF[mf * 2 + 1], bF[nf * 2 + 1], acc[4 + mf][nf]);
      }
    __builtin_amdgcn_s_setprio(0);
    if (kt + 2 < NT) { VMC4(); } else { VMC0(); }
    SBAR();
  }

  if (EPI == 0){
    #pragma unroll
    for (int mfg = 0; mfg < 8; mfg++){
      #pragma unroll
      for (int nf = 0; nf < 4; nf++){
        int col = n0 + wn * 64 + nf * 16 + l15;
        int row0 = m0 + wm * 128 + mfg * 16 + l4 * 4;
        #pragma unroll
        for (int r = 0; r < 4; r++)
          outF[(size_t)(row0 + r) * N + col] = acc[mfg][nf][r];
      }
    }
  } else {
    const int NH = N >> 1;
    #pragma unroll
    for (int mfg = 0; mfg < 8; mfg++){
      #pragma unroll
      for (int nfp = 0; nfp < 2; nfp++){
        int col = (n0 >> 1) + wn * 32 + nfp * 16 + l15;
        int row0 = m0 + wm * 128 + mfg * 16 + l4 * 4;
        #pragma unroll
        for (int r = 0; r < 4; r++){
          float u = acc[mfg][nfp * 2 + 0][r];
          float g = acc[mfg][nfp * 2 + 1][r];
          outH[(size_t)(row0 + r) * NH + col] = f2bf(u / (1.0f + __expf(-u)) * g);
        }
      }
    }
  }
}

// ---------------- q/k norm + rope + v transpose (Q pre-scaled by 0.125*log2e) ----------------
__global__ __launch_bounds__(256) void qkvpost_k(const float* __restrict__ qkv,
                                                 const float* __restrict__ qn,
                                                 const float* __restrict__ kn,
                                                 unsigned short* __restrict__ qb,
                                                 unsigned short* __restrict__ kb,
                                                 unsigned short* __restrict__ vt){
  const int t = blockIdx.x;
  const int lane = threadIdx.x & 63, w = threadIdx.x >> 6;
  const int d = lane;
  const int fi = d & 7;
  const float invf = powf(10000.0f, -(float)fi * 0.125f);
  const float ang = (float)t * invf;
  const float c = cosf(ang), s = sinf(ang);

  for (int i = 0; i < 4; i++){
    int h = w * 4 + i;
    float v = qkv[(size_t)t * 2560 + h * 128 + d];
    float ss = v * v;
    for (int m = 1; m < 64; m <<= 1) ss += __shfl_xor(ss, m);
    float r = rsqrtf(ss * (1.0f / D_H) + 1e-6f);
    float xn = v * r * (1.0f + qn[d]);
    float partner = __shfl_xor(xn, 8);
    float o;
    if (d < 8)       o = xn * c - partner * s;
    else if (d < 16) o = xn * c + partner * s;
    else             o = xn;
    qb[((size_t)h * T_LEN + t) * D_H + d] = f2bf(o * QSCALE);
  }
  {
    float v = qkv[(size_t)t * 2560 + 2048 + w * 64 + d];
    float ss = v * v;
    for (int m = 1; m < 64; m <<= 1) ss += __shfl_xor(ss, m);
    float r = rsqrtf(ss * (1.0f / D_H) + 1e-6f);
    float xn = v * r * (1.0f + kn[d]);
    float partner = __shfl_xor(xn, 8);
    float o;
    if (d < 8)       o = xn * c - partner * s;
    else if (d < 16) o = xn * c + partner * s;
    else             o = xn;
    kb[((size_t)w * T_LEN + t) * D_H + d] = f2bf(o);
  }
  {
    float v = qkv[(size_t)t * 2560 + 2304 + w * 64 + d];
    vt[((size_t)(w * 64 + d)) * T_LEN + t] = f2bf(v);
  }
}

// ---------------- flash attention, 1 wave, 16 q-rows, KV tiles of 64 ----------------
__global__ __launch_bounds__(64) void attn_k(const unsigned short* __restrict__ qb,
                                             const unsigned short* __restrict__ kb,
                                             const unsigned short* __restrict__ vt,
                                             const float* __restrict__ qkv,
                                             unsigned short* __restrict__ ctxg){
  const int qt = blockIdx.x, h = blockIdx.y;
  const int g = h >> 2;
  const int lane = threadIdx.x;
  const int l15 = lane & 15, l4 = lane >> 4;
  const int q0 = qt * 16;
  __shared__ unsigned short Pl[16][72];

  const bf16x8 aq0 = *(const bf16x8*)(qb + ((size_t)h * T_LEN + q0 + l15) * D_H + l4 * 8);
  const bf16x8 aq1 = *(const bf16x8*)(qb + ((size_t)h * T_LEN + q0 + l15) * D_H + 32 + l4 * 8);

  f32x4 acc[4] = {};
  float mrun[4], lpart[4];
  for (int j = 0; j < 4; j++){ mrun[j] = -1e30f; lpart[j] = 0.0f; }

  for (int kv0 = 0; kv0 <= q0 + 15; kv0 += 64){
    f32x4 sc[4];
    #pragma unroll
    for (int cp = 0; cp < 4; cp++){
      const unsigned short* kbase = kb + ((size_t)g * T_LEN + kv0 + cp * 16 + l15) * D_H + l4 * 8;
      bf16x8 bk0 = *(const bf16x8*)(kbase);
      bf16x8 bk1 = *(const bf16x8*)(kbase + 32);
      f32x4 z = {0.f, 0.f, 0.f, 0.f};
      z = mfma16(aq0, bk0, z);
      z = mfma16(aq1, bk1, z);
      sc[cp] = z;
    }
    float resc[4];
    #pragma unroll
    for (int j = 0; j < 4; j++){
      int r = q0 + l4 * 4 + j;
      #pragma unroll
      for (int cp = 0; cp < 4; cp++){
        int col = kv0 + cp * 16 + l15;
        sc[cp][j] = (col <= r) ? sc[cp][j] : -1e30f;
      }
      float mx = fmaxf(fmaxf(sc[0][j], sc[1][j]), fmaxf(sc[2][j], sc[3][j]));
      for (int off = 1; off < 16; off <<= 1) mx = fmaxf(mx, __shfl_xor(mx, off));
      float mnew = fmaxf(mrun[j], mx);
      resc[j] = exp2f(mrun[j] - mnew);
      mrun[j] = mnew;
      float ssum = 0.0f;
      #pragma unroll
      for (int cp = 0; cp < 4; cp++){
        float pv = exp2f(sc[cp][j] - mnew);
        sc[cp][j] = pv;
        ssum += pv;
      }
      lpart[j] = lpart[j] * resc[j] + ssum;
      #pragma unroll
      for (int nt = 0; nt < 4; nt++) acc[nt][j] *= resc[j];
    }
    __syncthreads();
    #pragma unroll
    for (int j = 0; j < 4; j++)
      #pragma unroll
      for (int cp = 0; cp < 4; cp++)
        Pl[l4 * 4 + j][cp * 16 + l15] = f2bf(sc[cp][j]);
    __syncthreads();
    const bf16x8 pa0 = *(const bf16x8*)&Pl[l15][l4 * 8];
    const bf16x8 pa1 = *(const bf16x8*)&Pl[l15][32 + l4 * 8];
    #pragma unroll
    for (int nt = 0; nt < 4; nt++){
      const unsigned short* vbase = vt + ((size_t)g * 64 + nt * 16 + l15) * T_LEN + kv0;
      bf16x8 bv0 = *(const bf16x8*)(vbase + l4 * 8);
      bf16x8 bv1 = *(const bf16x8*)(vbase + 32 + l4 * 8);
      acc[nt] = mfma16(pa1, bv1, mfma16(pa0, bv0, acc[nt]));
    }
  }

  #pragma unroll
  for (int j = 0; j < 4; j++)
    for (int off = 1; off < 16; off <<= 1) lpart[j] += __shfl_xor(lpart[j], off);

  #pragma unroll
  for (int j = 0; j < 4; j++){
    int r = q0 + l4 * 4 + j;
    float inv = 1.0f / lpart[j];
    #pragma unroll
    for (int nt = 0; nt < 4; nt++){
      int d = nt * 16 + l15;
      float gate = qkv[(size_t)r * 2560 + h * 128 + 64 + d];
      float val = acc[nt][j] * inv * (1.0f / (1.0f + __expf(-gate)));
      ctxg[(size_t)r * (H_N * D_H) + h * D_H + d] = f2bf(val);
    }
  }
}

extern "C" void kernel_launch(void* const* d_in, const int* in_sizes, int n_in,
                              void* d_out, int out_size, void* d_ws, size_t ws_size,
                              hipStream_t stream){
  (void)in_sizes; (void)n_in; (void)out_size; (void)ws_size;
  const int*   tokens = (const int*)d_in[0];
  const float* emb    = (const float*)d_in[1];
  const float* Wq     = (const float*)d_in[2];
  const float* Wk     = (const float*)d_in[3];
  const float* Wv     = (const float*)d_in[4];
  const float* Wo     = (const float*)d_in[5];
  const float* qn     = (const float*)d_in[6];
  const float* kn     = (const float*)d_in[7];
  const float* n1     = (const float*)d_in[8];
  const float* n2     = (const float*)d_in[9];
  const float* f1     = (const float*)d_in[10];
  const float* f2     = (const float*)d_in[11];
  const float* f3     = (const float*)d_in[12];
  const float* fn     = (const float*)d_in[13];
  const float* head   = (const float*)d_in[14];
  float* out = (float*)d_out;

  char* ws = (char*)d_ws;
  size_t off = 0;
  auto alloc = [&](size_t bytes)->char*{
    char* p = ws + off;
    off += (bytes + 255) & ~(size_t)255;
    return p;
  };
  float*          x       = (float*)alloc((size_t)T_LEN * E_DIM * 4);
  unsigned short* hbf     = (unsigned short*)alloc((size_t)T_LEN * E_DIM * 2);
  float*          qkvf    = (float*)alloc((size_t)T_LEN * 2560 * 4);
  unsigned short* qb      = (unsigned short*)alloc((size_t)H_N * T_LEN * D_H * 2);
  unsigned short* kb      = (unsigned short*)alloc((size_t)G_N * T_LEN * D_H * 2);
  unsigned short* vt      = (unsigned short*)alloc((size_t)G_N * D_H * T_LEN * 2);
  unsigned short* ctxg    = (unsigned short*)alloc((size_t)T_LEN * E_DIM * 2);
  unsigned short* hg      = (unsigned short*)alloc((size_t)T_LEN * F_DIM * 2);
  unsigned short* wt_qkv  = (unsigned short*)alloc((size_t)2560 * E_DIM * 2);
  unsigned short* wt_o    = (unsigned short*)alloc((size_t)E_DIM * E_DIM * 2);
  unsigned short* wt_f12i = (unsigned short*)alloc((size_t)2 * F_DIM * E_DIM * 2);
  unsigned short* wt_f3   = (unsigned short*)alloc((size_t)E_DIM * F_DIM * 2);
  unsigned short* wt_head = (unsigned short*)alloc((size_t)V_SZ * E_DIM * 2);

  embed_k<<<T_LEN, 256, 0, stream>>>(emb, tokens, x);
  transpose_bf16<<<dim3(V_SZ / 32, E_DIM / 32), 256, 0, stream>>>(head, wt_head, E_DIM, V_SZ);

  for (int l = 0; l < L_N; l++){
    prep_weights<<<15872, 256, 0, stream>>>(Wq + (size_t)l * E_DIM * 2048,
                                            Wk + (size_t)l * E_DIM * 256,
                                            Wv + (size_t)l * E_DIM * 256,
                                            Wo + (size_t)l * E_DIM * E_DIM,
                                            f1 + (size_t)l * E_DIM * F_DIM,
                                            f2 + (size_t)l * E_DIM * F_DIM,
                                            f3 + (size_t)l * F_DIM * E_DIM,
                                            wt_qkv, wt_o, wt_f12i, wt_f3);

    rmsnorm_k<<<T_LEN, 256, 0, stream>>>(x, n1 + l * E_DIM, hbf);
    gemm64_bt<false><<<(T_LEN / 64) * (2560 / 128), 256, 0, stream>>>(hbf, wt_qkv, qkvf, T_LEN, 2560, E_DIM);
    qkvpost_k<<<T_LEN, 256, 0, stream>>>(qkvf, qn + l * D_H, kn + l * D_H, qb, kb, vt);
    attn_k<<<dim3(T_LEN / 16, H_N), 64, 0, stream>>>(qb, kb, vt, qkvf, ctxg);
    gemm64_bt<true><<<(T_LEN / 64) * (E_DIM / 128), 256, 0, stream>>>(ctxg, wt_o, x, T_LEN, E_DIM, E_DIM);

    rmsnorm_k<<<T_LEN, 256, 0, stream>>>(x, n2 + l * E_DIM, hbf);
    gemm256<1><<<(T_LEN / 256) * (2 * F_DIM / 256), 512, 0, stream>>>(hbf, wt_f12i, nullptr, hg, T_LEN, 2 * F_DIM, E_DIM);
    gemm64_bt<true><<<(T_LEN / 64) * (E_DIM / 128), 256, 0, stream>>>(hg, wt_f3, x, T_LEN, E_DIM, F_DIM);
  }

  rmsnorm_k<<<T_LEN, 256, 0, stream>>>(x, fn, hbf);
  gemm256<0><<<(T_LEN / 256) * (V_SZ / 256), 512, 0, stream>>>(hbf, wt_head, out, nullptr, T_LEN, V_SZ, E_DIM);
}